// Round 10
// baseline (949.746 us; speedup 1.0000x reference)
//
#include <hip/hip_runtime.h>
#include <hip/hip_bf16.h>
#include <math.h>

// GNN: 3-layer GCN + BN + GELU + residual + meanpool + MLP -> scalar.
// R10: R9 (668us) + bucketed CSR fill. R9's fill_kernel wrote 105MB to HBM
// (16x amplification: scattered 4B stores into 100k random append regions).
// Fix: (1) stage: append packed (row<<7|col&127) into 128-node bucket regions
// (appends per bucket are sequential -> lines merge in shared L3); (2) one
// block per bucket places entries into exact CSR slots via LDS cursors
// (writes land in an 8KB window, fully coalesced). agg/gemm/stats unchanged.

__device__ __forceinline__ float gelu_f(float x) {
    return 0.5f * x * (1.0f + erff(x * 0.7071067811865476f));
}

__device__ __forceinline__ int wave_incl_scan(int v, int lane) {
#pragma unroll
    for (int off = 1; off < 64; off <<= 1) {
        int t = __shfl_up(v, (unsigned)off, 64);
        if (lane >= off) v += t;
    }
    return v;
}

// ---- init: deg = 1.0 (self loop), zero double accumulators ----
__global__ void init_kernel(float* __restrict__ deg, double* __restrict__ dbls,
                            int n, int ndbl) {
    int i = blockIdx.x * 256 + threadIdx.x;
    if (i < n) deg[i] = 1.0f;
    if (i < ndbl) dbls[i] = 0.0;
}

__global__ void degree_kernel(const int* __restrict__ col, float* __restrict__ deg, int E) {
    int e = blockIdx.x * 256 + threadIdx.x;
    if (e < E) atomicAdd(&deg[col[e]], 1.0f);
}

__global__ __launch_bounds__(256) void scan1_kernel(const float* __restrict__ deg,
                                                    float* __restrict__ dinv,
                                                    int* __restrict__ offs,
                                                    int* __restrict__ bsums, int n) {
    int i = blockIdx.x * 256 + threadIdx.x;
    int lane = threadIdx.x & 63;
    int wid = threadIdx.x >> 6;
    int cnt = 0;
    if (i < n) {
        float d = deg[i];
        dinv[i] = 1.0f / sqrtf(d);
        cnt = (int)d - 1;
    }
    int incl = wave_incl_scan(cnt, lane);
    __shared__ int ws[4];
    if (lane == 63) ws[wid] = incl;
    __syncthreads();
    if (threadIdx.x == 0) {
        int a = 0;
#pragma unroll
        for (int j = 0; j < 4; j++) { int t = ws[j]; ws[j] = a; a += t; }
        bsums[blockIdx.x] = a;
    }
    __syncthreads();
    int excl = incl - cnt + ws[wid];
    if (i < n) offs[i] = excl;
}

__global__ __launch_bounds__(512) void scan2_kernel(int* __restrict__ bsums, int nblk) {
    int lane = threadIdx.x & 63;
    int wid = threadIdx.x >> 6;
    int v = (threadIdx.x < nblk) ? bsums[threadIdx.x] : 0;
    int incl = wave_incl_scan(v, lane);
    __shared__ int ws[8];
    if (lane == 63) ws[wid] = incl;
    __syncthreads();
    if (threadIdx.x == 0) {
        int a = 0;
#pragma unroll
        for (int j = 0; j < 8; j++) { int t = ws[j]; ws[j] = a; a += t; }
    }
    __syncthreads();
    int excl = incl - v + ws[wid];
    if (threadIdx.x < nblk) bsums[threadIdx.x] = excl;
}

// scan3: finalize offs; also init bucket cursors (bucket = 128 nodes)
__global__ void scan3_kernel(int* __restrict__ offs, const int* __restrict__ bsums,
                             int* __restrict__ bcur, int n) {
    int i = blockIdx.x * 256 + threadIdx.x;
    if (i < n) {
        int o = offs[i] + bsums[i >> 8];
        offs[i] = o;
        if ((i & 127) == 0) bcur[i >> 7] = o;
    }
}

// ---- bucketed fill pass 1: append packed (row<<7 | col&127) to bucket region ----
__global__ void stage_kernel(const int* __restrict__ row, const int* __restrict__ col,
                             int* __restrict__ bcur, unsigned int* __restrict__ stage, int E) {
    int e = blockIdx.x * 256 + threadIdx.x;
    if (e < E) {
        int c = col[e];
        int b = c >> 7;
        int p = atomicAdd(&bcur[b], 1);
        stage[p] = ((unsigned int)row[e] << 7) | (unsigned int)(c & 127);
    }
}

// ---- bucketed fill pass 2: one block per bucket, LDS cursors -> exact csr ----
__global__ __launch_bounds__(256) void bucket_sort_kernel(const unsigned int* __restrict__ stage,
                                                          const int* __restrict__ offs,
                                                          int* __restrict__ csr, int N, int E) {
    __shared__ int cur[128];
    int b = blockIdx.x;
    int nb0 = b << 7;
    int base = offs[nb0];
    int nend = nb0 + 128;
    int end = (nend < N) ? offs[nend] : E;
    if (threadIdx.x < 128) {
        int node = nb0 + threadIdx.x;
        cur[threadIdx.x] = (node < N) ? (offs[node] - base) : 0;
    }
    __syncthreads();
    int cnt = end - base;
    for (int t = threadIdx.x; t < cnt; t += 256) {
        unsigned int v = stage[base + t];
        int lc = v & 127;
        int src = (int)(v >> 7);
        int pos = atomicAdd(&cur[lc], 1);
        csr[base + pos] = src;
    }
}

// ---- aggregation (R2-exact gather loop) + spread-atomic fused BN stats ----
// PRE=true : Out[i] = dinv_i * (dinv_i*U_i + sum_j dinv_j*U_j)         (no bias)
// PRE=false: Out[i] = dinv_i * (U_i + sum_j U_j) + bias                (U pre-scaled)
template <int D, bool PRE, bool STATS, bool BIAS>
__global__ __launch_bounds__(256) void agg_kernel(const float* __restrict__ U,
                                                  const int* __restrict__ csr,
                                                  const int* __restrict__ offs,
                                                  const float* __restrict__ deg,
                                                  const float* __restrict__ dinv,
                                                  const float* __restrict__ bias,
                                                  float* __restrict__ Out,
                                                  double* __restrict__ tmp, int n) {
    constexpr int GPN = D / 4;          // lanes per node (32 for D=128, 16 for D=64)
    constexpr int NPB = 256 / GPN;
    int g = threadIdx.x / GPN;
    int cl = threadIdx.x % GPN;
    int node = blockIdx.x * NPB + g;
    bool act = node < n;
    int c4 = cl * 4;

    float4 a0 = make_float4(0.f, 0.f, 0.f, 0.f), a1 = a0;
    int start = 0, cnt = 0;
    float dvi = 0.f;
    if (act) {
        start = offs[node];
        cnt = (int)deg[node] - 1;
        dvi = dinv[node];
        float4 self = *(const float4*)(U + (size_t)node * D + c4);
        if (PRE) {
            a0.x = self.x * dvi; a0.y = self.y * dvi;
            a0.z = self.z * dvi; a0.w = self.w * dvi;
        } else {
            a0 = self;
        }
    }
    int j = 0;
    for (; j + 4 <= cnt; j += 4) {
        int s0 = csr[start + j];
        int s1 = csr[start + j + 1];
        int s2 = csr[start + j + 2];
        int s3 = csr[start + j + 3];
        float4 v0 = *(const float4*)(U + (size_t)s0 * D + c4);
        float4 v1 = *(const float4*)(U + (size_t)s1 * D + c4);
        float4 v2 = *(const float4*)(U + (size_t)s2 * D + c4);
        float4 v3 = *(const float4*)(U + (size_t)s3 * D + c4);
        if (PRE) {
            float d0 = dinv[s0], d1 = dinv[s1], d2 = dinv[s2], d3 = dinv[s3];
            v0.x *= d0; v0.y *= d0; v0.z *= d0; v0.w *= d0;
            v1.x *= d1; v1.y *= d1; v1.z *= d1; v1.w *= d1;
            v2.x *= d2; v2.y *= d2; v2.z *= d2; v2.w *= d2;
            v3.x *= d3; v3.y *= d3; v3.z *= d3; v3.w *= d3;
        }
        a0.x += v0.x; a0.y += v0.y; a0.z += v0.z; a0.w += v0.w;
        a1.x += v1.x; a1.y += v1.y; a1.z += v1.z; a1.w += v1.w;
        a0.x += v2.x; a0.y += v2.y; a0.z += v2.z; a0.w += v2.w;
        a1.x += v3.x; a1.y += v3.y; a1.z += v3.z; a1.w += v3.w;
    }
    for (; j < cnt; j++) {
        int s = csr[start + j];
        float4 v = *(const float4*)(U + (size_t)s * D + c4);
        if (PRE) {
            float d = dinv[s];
            v.x *= d; v.y *= d; v.z *= d; v.w *= d;
        }
        a0.x += v.x; a0.y += v.y; a0.z += v.z; a0.w += v.w;
    }
    float4 acc;
    acc.x = a0.x + a1.x; acc.y = a0.y + a1.y;
    acc.z = a0.z + a1.z; acc.w = a0.w + a1.w;

    float h[4];
    h[0] = acc.x * dvi; h[1] = acc.y * dvi;
    h[2] = acc.z * dvi; h[3] = acc.w * dvi;
    if (BIAS) {
        float4 b4 = *(const float4*)(bias + c4);
        h[0] += b4.x; h[1] += b4.y; h[2] += b4.z; h[3] += b4.w;
    }
    if (act) {
        *(float4*)(Out + (size_t)node * D + c4) = make_float4(h[0], h[1], h[2], h[3]);
    } else {
        h[0] = h[1] = h[2] = h[3] = 0.f;   // no stats contribution
    }

    if (STATS) {
        float s[4], q[4];
#pragma unroll
        for (int c = 0; c < 4; c++) { s[c] = h[c]; q[c] = h[c] * h[c]; }
#pragma unroll
        for (int m = GPN; m < 64; m <<= 1) {
#pragma unroll
            for (int c = 0; c < 4; c++) {
                s[c] += __shfl_xor(s[c], m, 64);
                q[c] += __shfl_xor(q[c], m, 64);
            }
        }
        __shared__ float ps[4][GPN][4], pq[4][GPN][4];
        int wid = threadIdx.x >> 6;
        int lane = threadIdx.x & 63;
        if (lane < GPN) {
#pragma unroll
            for (int c = 0; c < 4; c++) { ps[wid][lane][c] = s[c]; pq[wid][lane][c] = q[c]; }
        }
        __syncthreads();
        if (threadIdx.x < D) {
            int cgi = threadIdx.x >> 2, ci = threadIdx.x & 3;
            float t1 = ps[0][cgi][ci] + ps[1][cgi][ci] + ps[2][cgi][ci] + ps[3][cgi][ci];
            float t2 = pq[0][cgi][ci] + pq[1][cgi][ci] + pq[2][cgi][ci] + pq[3][cgi][ci];
            int cp = (blockIdx.x & 63) * 2 * D;
            atomicAdd(&tmp[cp + threadIdx.x], (double)t1);
            atomicAdd(&tmp[cp + D + threadIdx.x], (double)t2);
        }
    }
}

// ---- register-blocked GEMM ----
// BNIN: scale/shift+GELU on input staging. STATS: spread-atomic sum/sumsq.
template <int DIN, int DOUT, bool BNIN, bool BIAS, bool DINVOUT, bool STATS>
__global__ __launch_bounds__(256) void gemm_kernel(const float* __restrict__ Hin,
                                                   const float* __restrict__ W,
                                                   const float* __restrict__ scale,
                                                   const float* __restrict__ shift,
                                                   const float* __restrict__ bias,
                                                   const float* __restrict__ dinv,
                                                   float* __restrict__ Out,
                                                   double* __restrict__ tmp, int n) {
    constexpr int BNODES = 64;
    constexpr int KT = 32;
    constexpr int HP = DIN + 4;
    constexpr int VC = DOUT / 16;      // 8 (DOUT=128) or 4 (DOUT=64)
    constexpr int C4 = VC / 4;
    __shared__ float Hs[BNODES * HP];
    __shared__ float Ws[KT * DOUT];
    __shared__ float ps[STATS ? 4 : 1][16][VC];
    __shared__ float pq[STATS ? 4 : 1][16][VC];

    int node0 = blockIdx.x * BNODES;
    int nv = n - node0;
    if (nv > BNODES) nv = BNODES;
    int cg = threadIdx.x & 15;
    int ng = threadIdx.x >> 4;

    constexpr int F4 = BNODES * (DIN / 4);
    for (int f = threadIdx.x; f < F4; f += 256) {
        int nn = f / (DIN / 4);
        int k4 = f - nn * (DIN / 4);
        float4 v = make_float4(0.f, 0.f, 0.f, 0.f);
        if (nn < nv)
            v = *(const float4*)(Hin + (size_t)(node0 + nn) * DIN + k4 * 4);
        if (BNIN) {
            float4 sc = *(const float4*)(scale + k4 * 4);
            float4 sh = *(const float4*)(shift + k4 * 4);
            v.x = gelu_f(fmaf(v.x, sc.x, sh.x));
            v.y = gelu_f(fmaf(v.y, sc.y, sh.y));
            v.z = gelu_f(fmaf(v.z, sc.z, sh.z));
            v.w = gelu_f(fmaf(v.w, sc.w, sh.w));
        }
        *(float4*)(Hs + nn * HP + k4 * 4) = v;
    }

    float acc[4][VC];
#pragma unroll
    for (int i = 0; i < 4; i++)
#pragma unroll
        for (int c = 0; c < VC; c++) acc[i][c] = 0.0f;

    for (int kb = 0; kb < DIN; kb += KT) {
        __syncthreads();
        for (int f = threadIdx.x; f < KT * DOUT / 4; f += 256)
            *(float4*)(Ws + f * 4) = *(const float4*)(W + (size_t)kb * DOUT + f * 4);
        __syncthreads();
#pragma unroll
        for (int kk = 0; kk < KT; kk++) {
            float h[4];
#pragma unroll
            for (int i = 0; i < 4; i++)
                h[i] = Hs[(ng * 4 + i) * HP + kb + kk];
            float w[VC];
#pragma unroll
            for (int c = 0; c < C4; c++) {
                float4 w4 = *(const float4*)(Ws + kk * DOUT + cg * VC + c * 4);
                w[c * 4 + 0] = w4.x; w[c * 4 + 1] = w4.y;
                w[c * 4 + 2] = w4.z; w[c * 4 + 3] = w4.w;
            }
#pragma unroll
            for (int i = 0; i < 4; i++)
#pragma unroll
                for (int c = 0; c < VC; c++)
                    acc[i][c] = fmaf(h[i], w[c], acc[i][c]);
        }
    }

    float fin[4][VC];
#pragma unroll
    for (int i = 0; i < 4; i++) {
        int nn = ng * 4 + i;
        bool valid = nn < nv;
        int node = node0 + nn;
        float dv = 1.0f;
        if (DINVOUT && valid) dv = dinv[node];
#pragma unroll
        for (int c = 0; c < VC; c++) {
            float f = acc[i][c] * dv;
            if (BIAS) f += bias[cg * VC + c];
            fin[i][c] = valid ? f : 0.f;
        }
        if (valid) {
#pragma unroll
            for (int c = 0; c < C4; c++)
                *(float4*)(Out + (size_t)node * DOUT + cg * VC + c * 4) =
                    make_float4(fin[i][c * 4 + 0], fin[i][c * 4 + 1],
                                fin[i][c * 4 + 2], fin[i][c * 4 + 3]);
        }
    }

    if (STATS) {
        float s[VC], q[VC];
#pragma unroll
        for (int c = 0; c < VC; c++) {
            s[c] = fin[0][c] + fin[1][c] + fin[2][c] + fin[3][c];
            q[c] = fin[0][c] * fin[0][c] + fin[1][c] * fin[1][c] +
                   fin[2][c] * fin[2][c] + fin[3][c] * fin[3][c];
        }
#pragma unroll
        for (int st = 16; st < 64; st <<= 1) {
#pragma unroll
            for (int c = 0; c < VC; c++) {
                s[c] += __shfl_xor(s[c], st, 64);
                q[c] += __shfl_xor(q[c], st, 64);
            }
        }
        int wid = threadIdx.x >> 6;
        int lane = threadIdx.x & 63;
        if (lane < 16) {
#pragma unroll
            for (int c = 0; c < VC; c++) { ps[wid][lane][c] = s[c]; pq[wid][lane][c] = q[c]; }
        }
        __syncthreads();
        if (threadIdx.x < DOUT) {
            int col = threadIdx.x;
            int cgi = col / VC, ci = col % VC;
            float t = ps[0][cgi][ci] + ps[1][cgi][ci] + ps[2][cgi][ci] + ps[3][cgi][ci];
            float t2 = pq[0][cgi][ci] + pq[1][cgi][ci] + pq[2][cgi][ci] + pq[3][cgi][ci];
            int cp = (blockIdx.x & 63) * 2 * DOUT;
            atomicAdd(&tmp[cp + col], (double)t);
            atomicAdd(&tmp[cp + DOUT + col], (double)t2);
        }
    }
}

// ---- fold 64 tmp copies -> per-channel scale/shift floats ----
template <int D>
__global__ void finalize_tmp_kernel(const double* __restrict__ tmp,
                                    const float* __restrict__ g, const float* __restrict__ be,
                                    float* __restrict__ scale, float* __restrict__ shift, int n) {
    int c = threadIdx.x;
    if (c < D) {
        double s = 0.0, q = 0.0;
        for (int gg = 0; gg < 64; gg++) {
            s += tmp[gg * 2 * D + c];
            q += tmp[gg * 2 * D + D + c];
        }
        double mu = s / n;
        double var = q / n - mu * mu;
        double inv = 1.0 / sqrt(var + 1e-5);
        double sc = (double)g[c] * inv;
        scale[c] = (float)sc;
        shift[c] = (float)((double)be[c] - mu * sc);
    }
}

// ---- fold 64 tmp copies -> raw stats sums (for norm_pool) ----
template <int D>
__global__ void combine_kernel(const double* __restrict__ tmp, double* __restrict__ stats) {
    int t = threadIdx.x;
    if (t < 2 * D) {
        double s = 0.0;
        for (int gg = 0; gg < 64; gg++) s += tmp[gg * 2 * D + t];
        stats[t] = s;
    }
}

// ---- layer-3: BN normalize + GELU + residual(x) + mean-pool accumulate ----
__global__ __launch_bounds__(256) void norm_pool_kernel(const float* __restrict__ X3,
                                                        const float* __restrict__ x0,
                                                        const double* __restrict__ stats,
                                                        const float* __restrict__ gw,
                                                        const float* __restrict__ be,
                                                        double* __restrict__ pool, int n) {
    constexpr int D = 64;
    constexpr int RPB = 4;
    int c = threadIdx.x % D;
    double mu = stats[c] / n;
    double var = stats[c + D] / n - mu * mu;
    double inv = 1.0 / sqrt(var + 1e-5);
    float scale = (float)((double)gw[c] * inv);
    float shift = (float)((double)be[c] - mu * (double)gw[c] * inv);
    int r0 = threadIdx.x / D;
    int rowsPerGrid = gridDim.x * RPB;
    double s = 0.0;
    for (int r = blockIdx.x * RPB + r0; r < n; r += rowsPerGrid) {
        size_t idx = (size_t)r * D + c;
        float t = fmaf(X3[idx], scale, shift);
        float res = x0[idx] + gelu_f(t);
        s += res;
    }
    __shared__ double sh[256];
    sh[threadIdx.x] = s;
    __syncthreads();
    if (threadIdx.x < D) {
#pragma unroll
        for (int j = 1; j < RPB; j++) s += sh[threadIdx.x + j * D];
        atomicAdd(&pool[c], s);
    }
}

// ---- head MLP: 64 ->128 ->64 ->32 ->1, single block ----
__global__ __launch_bounds__(128) void mlp_kernel(const double* __restrict__ pool,
                                                  const float* __restrict__ w1, const float* __restrict__ b1,
                                                  const float* __restrict__ w2, const float* __restrict__ b2,
                                                  const float* __restrict__ w3, const float* __restrict__ b3,
                                                  const float* __restrict__ w4, const float* __restrict__ b4,
                                                  float* __restrict__ out, int n) {
    __shared__ float v0[64], h1[128], h2[64], h3[32];
    int t = threadIdx.x;
    if (t < 64) v0[t] = (float)(pool[t] / (double)n);
    __syncthreads();
    if (t < 128) {
        float a = b1[t];
        for (int k = 0; k < 64; k++) a = fmaf(v0[k], w1[k * 128 + t], a);
        h1[t] = gelu_f(a);
    }
    __syncthreads();
    if (t < 64) {
        float a = b2[t];
        for (int k = 0; k < 128; k++) a = fmaf(h1[k], w2[k * 64 + t], a);
        h2[t] = gelu_f(a);
    }
    __syncthreads();
    if (t < 32) {
        float a = b3[t];
        for (int k = 0; k < 64; k++) a = fmaf(h2[k], w3[k * 32 + t], a);
        h3[t] = gelu_f(a);
    }
    __syncthreads();
    if (t == 0) {
        float a = b4[0];
        for (int k = 0; k < 32; k++) a = fmaf(h3[k], w4[k], a);
        out[0] = a;
    }
}

extern "C" void kernel_launch(void* const* d_in, const int* in_sizes, int n_in,
                              void* d_out, int out_size, void* d_ws, size_t ws_size,
                              hipStream_t stream) {
    const float* x    = (const float*)d_in[0];
    const int*   ei   = (const int*)d_in[1];
    const float* W1   = (const float*)d_in[2];
    const float* b1   = (const float*)d_in[3];
    const float* g1   = (const float*)d_in[4];
    const float* be1  = (const float*)d_in[5];
    const float* W2   = (const float*)d_in[6];
    const float* b2   = (const float*)d_in[7];
    const float* g2   = (const float*)d_in[8];
    const float* be2  = (const float*)d_in[9];
    const float* W3   = (const float*)d_in[10];
    const float* b3   = (const float*)d_in[11];
    const float* g3   = (const float*)d_in[12];
    const float* be3  = (const float*)d_in[13];
    const float* fc1w = (const float*)d_in[14];
    const float* fc1b = (const float*)d_in[15];
    const float* fc2w = (const float*)d_in[16];
    const float* fc2b = (const float*)d_in[17];
    const float* fc3w = (const float*)d_in[18];
    const float* fc3b = (const float*)d_in[19];
    const float* fc4w = (const float*)d_in[20];
    const float* fc4b = (const float*)d_in[21];

    const int N = in_sizes[0] / 64;
    const int E = in_sizes[1] / 2;
    const int* e_row = ei;       // source
    const int* e_col = ei + E;   // target (aggregation index)
    const int nbuckets = (N + 127) >> 7;

    // ---- workspace layout (~117 MB) ----
    char* ws = (char*)d_ws;
    size_t off = 0;
    double* pool   = (double*)(ws + off); off += 64 * sizeof(double);
    double* tmp1   = (double*)(ws + off); off += 64 * 256 * sizeof(double);  // gemm1 stats spread
    double* tmp2   = (double*)(ws + off); off += 64 * 256 * sizeof(double);  // agg2 stats spread
    double* tmp3   = (double*)(ws + off); off += 64 * 128 * sizeof(double);  // agg3 stats spread
    double* stats3 = (double*)(ws + off); off += 128 * sizeof(double);
    const int NDBL = 64 + 64 * 256 * 2 + 64 * 128 + 128;  // zeroed by init
    float* scale1 = (float*)(ws + off); off += 128 * sizeof(float);
    float* shift1 = (float*)(ws + off); off += 128 * sizeof(float);
    float* scale2 = (float*)(ws + off); off += 128 * sizeof(float);
    float* shift2 = (float*)(ws + off); off += 128 * sizeof(float);
    float* deg   = (float*)(ws + off); off += (size_t)N * sizeof(float);
    float* dinv  = (float*)(ws + off); off += (size_t)N * sizeof(float);
    off = (off + 15) & ~(size_t)15;
    int* offs    = (int*)(ws + off); off += (size_t)N * sizeof(int);
    int* bcur    = (int*)(ws + off); off += 1024 * sizeof(int);
    int* bsums   = (int*)(ws + off); off += 512 * sizeof(int);
    int* csr     = (int*)(ws + off); off += (size_t)E * sizeof(int);
    unsigned int* stage = (unsigned int*)(ws + off); off += (size_t)E * sizeof(unsigned int);
    off = (off + 255) & ~(size_t)255;
    float* U     = (float*)(ws + off); off += (size_t)N * 128 * sizeof(float);  // gather table
    float* H     = (float*)(ws + off); off += (size_t)N * 128 * sizeof(float);  // row-major
    // alias: A1 = U head [N][64] (consumed by gemm1 before gemm2 overwrites U)
    float* A1 = U;

    const int nb256 = (N + 255) / 256;
    const int ebl = (E + 255) / 256;

    init_kernel<<<nb256, 256, 0, stream>>>(deg, pool, N, NDBL);
    degree_kernel<<<ebl, 256, 0, stream>>>(e_col, deg, E);
    scan1_kernel<<<nb256, 256, 0, stream>>>(deg, dinv, offs, bsums, N);
    scan2_kernel<<<1, 512, 0, stream>>>(bsums, nb256);
    scan3_kernel<<<nb256, 256, 0, stream>>>(offs, bsums, bcur, N);
    stage_kernel<<<ebl, 256, 0, stream>>>(e_row, e_col, bcur, stage, E);
    bucket_sort_kernel<<<nbuckets, 256, 0, stream>>>(stage, offs, csr, N, E);

    // Layer 1: agg x in 64-dim (PRE) -> A1; GEMM(+b1,+stats->tmp1) -> H1
    agg_kernel<64, true, false, false><<<(N + 15) / 16, 256, 0, stream>>>(
        x, csr, offs, deg, dinv, nullptr, A1, nullptr, N);
    gemm_kernel<64, 128, false, true, false, true><<<(N + 63) / 64, 256, 0, stream>>>(
        A1, W1, nullptr, nullptr, b1, dinv, H, tmp1, N);
    finalize_tmp_kernel<128><<<1, 128, 0, stream>>>(tmp1, g1, be1, scale1, shift1, N);

    // Layer 2: GEMM (BN1+GELU fused, dinv prescale) -> U; agg(+b2,+stats->tmp2) -> H2
    gemm_kernel<128, 128, true, false, true, false><<<(N + 63) / 64, 256, 0, stream>>>(
        H, W2, scale1, shift1, nullptr, dinv, U, nullptr, N);
    agg_kernel<128, false, true, true><<<(N + 7) / 8, 256, 0, stream>>>(
        U, csr, offs, deg, dinv, b2, H, tmp2, N);
    finalize_tmp_kernel<128><<<1, 128, 0, stream>>>(tmp2, g2, be2, scale2, shift2, N);

    // Layer 3: GEMM (BN2+GELU fused, dinv prescale) 128->64 -> U; agg(+b3,+stats->tmp3) -> H3
    gemm_kernel<128, 64, true, false, true, false><<<(N + 63) / 64, 256, 0, stream>>>(
        H, W3, scale2, shift2, nullptr, dinv, U, nullptr, N);
    agg_kernel<64, false, true, true><<<(N + 15) / 16, 256, 0, stream>>>(
        U, csr, offs, deg, dinv, b3, H, tmp3, N);
    combine_kernel<64><<<1, 128, 0, stream>>>(tmp3, stats3);

    // Epilogue: BN3+GELU+residual+meanpool, then head MLP
    norm_pool_kernel<<<1024, 256, 0, stream>>>(H, x, stats3, g3, be3, pool, N);
    mlp_kernel<<<1, 128, 0, stream>>>(pool, fc1w, fc1b, fc2w, fc2b, fc3w, fc3b,
                                      fc4w, fc4b, (float*)d_out, N);
}

// Round 11
// 562.636 us; speedup vs baseline: 1.6880x; 1.6880x over previous
//
#include <hip/hip_runtime.h>
#include <hip/hip_bf16.h>
#include <hip/hip_fp16.h>
#include <math.h>

// GNN: 3-layer GCN + BN + GELU + residual + meanpool + MLP -> scalar.
// R11: R9 structure (revert R10 bucketing - atomic chains + XCD write amp)
// + fp16 gather tables REINSTATED: R4/R5's "fp16 regression" decomposes as
// ~62us gather + ~94us stats-atomic tail (6250-block chains). With R9's
// 64-way spread atomics the tail is ~1.5us, so fp16 halves gather bytes
// cleanly. Geometry: 16B/lane uint4, D/8 lanes/node, x4 unroll (R5 loop).

__device__ __forceinline__ float gelu_f(float x) {
    return 0.5f * x * (1.0f + erff(x * 0.7071067811865476f));
}

__device__ __forceinline__ int wave_incl_scan(int v, int lane) {
#pragma unroll
    for (int off = 1; off < 64; off <<= 1) {
        int t = __shfl_up(v, (unsigned)off, 64);
        if (lane >= off) v += t;
    }
    return v;
}

__device__ __forceinline__ void load8h(const __half* __restrict__ p, float* f) {
    uint4 u = *(const uint4*)p;
    const __half2* h2p = (const __half2*)&u;
#pragma unroll
    for (int i = 0; i < 4; i++) {
        float2 t = __half22float2(h2p[i]);
        f[2 * i] = t.x;
        f[2 * i + 1] = t.y;
    }
}

__device__ __forceinline__ void acc8h(const uint4& u, float* f) {
    const __half2* h2p = (const __half2*)&u;
#pragma unroll
    for (int i = 0; i < 4; i++) {
        float2 t = __half22float2(h2p[i]);
        f[2 * i] += t.x;
        f[2 * i + 1] += t.y;
    }
}

// ---- init: deg = 1.0 (self loop), zero double accumulators ----
__global__ void init_kernel(float* __restrict__ deg, double* __restrict__ dbls,
                            int n, int ndbl) {
    int i = blockIdx.x * 256 + threadIdx.x;
    if (i < n) deg[i] = 1.0f;
    if (i < ndbl) dbls[i] = 0.0;
}

__global__ void degree_kernel(const int* __restrict__ col, float* __restrict__ deg, int E) {
    int e = blockIdx.x * 256 + threadIdx.x;
    if (e < E) atomicAdd(&deg[col[e]], 1.0f);
}

__global__ __launch_bounds__(256) void scan1_kernel(const float* __restrict__ deg,
                                                    float* __restrict__ dinv,
                                                    int* __restrict__ offs,
                                                    int* __restrict__ bsums, int n) {
    int i = blockIdx.x * 256 + threadIdx.x;
    int lane = threadIdx.x & 63;
    int wid = threadIdx.x >> 6;
    int cnt = 0;
    if (i < n) {
        float d = deg[i];
        dinv[i] = 1.0f / sqrtf(d);
        cnt = (int)d - 1;
    }
    int incl = wave_incl_scan(cnt, lane);
    __shared__ int ws[4];
    if (lane == 63) ws[wid] = incl;
    __syncthreads();
    if (threadIdx.x == 0) {
        int a = 0;
#pragma unroll
        for (int j = 0; j < 4; j++) { int t = ws[j]; ws[j] = a; a += t; }
        bsums[blockIdx.x] = a;
    }
    __syncthreads();
    int excl = incl - cnt + ws[wid];
    if (i < n) offs[i] = excl;
}

__global__ __launch_bounds__(512) void scan2_kernel(int* __restrict__ bsums, int nblk) {
    int lane = threadIdx.x & 63;
    int wid = threadIdx.x >> 6;
    int v = (threadIdx.x < nblk) ? bsums[threadIdx.x] : 0;
    int incl = wave_incl_scan(v, lane);
    __shared__ int ws[8];
    if (lane == 63) ws[wid] = incl;
    __syncthreads();
    if (threadIdx.x == 0) {
        int a = 0;
#pragma unroll
        for (int j = 0; j < 8; j++) { int t = ws[j]; ws[j] = a; a += t; }
    }
    __syncthreads();
    int excl = incl - v + ws[wid];
    if (threadIdx.x < nblk) bsums[threadIdx.x] = excl;
}

__global__ void scan3_kernel(int* __restrict__ offs, const int* __restrict__ bsums,
                             int* __restrict__ cursor, int n) {
    int i = blockIdx.x * 256 + threadIdx.x;
    if (i < n) {
        int o = offs[i] + bsums[i >> 8];
        offs[i] = o;
        cursor[i] = o;
    }
}

__global__ void fill_kernel(const int* __restrict__ row, const int* __restrict__ col,
                            int* __restrict__ cursor, int* __restrict__ csr, int E) {
    int e = blockIdx.x * 256 + threadIdx.x;
    if (e < E) {
        int c = col[e];
        int pos = atomicAdd(&cursor[c], 1);
        csr[pos] = row[e];
    }
}

// ---- convert x[N][64] fp32 -> xh[N][64] fp16, scaled by dinv[node] ----
__global__ __launch_bounds__(256) void halfconv_kernel(const float* __restrict__ x,
                                                       const float* __restrict__ dinv,
                                                       __half* __restrict__ xh, int N) {
    int t = blockIdx.x * 256 + threadIdx.x;   // one 8-float chunk per thread
    if (t >= N * 8) return;
    int node = t >> 3;
    float dv = dinv[node];
    const float4* p = (const float4*)(x + (size_t)t * 8);
    float4 a = p[0], b = p[1];
    __half2 h[4];
    h[0] = __floats2half2_rn(a.x * dv, a.y * dv);
    h[1] = __floats2half2_rn(a.z * dv, a.w * dv);
    h[2] = __floats2half2_rn(b.x * dv, b.y * dv);
    h[3] = __floats2half2_rn(b.z * dv, b.w * dv);
    *(uint4*)(xh + (size_t)t * 8) = *(uint4*)h;
}

// ---- aggregation: H[i][D] = dinv_i*(Ut[i] + sum in-edge Ut[src]) (+bias) ----
// Ut fp16 row-major, pre-scaled by dinv[src]; fp32 accumulate.
// GPN = D/8 lanes per node, 16B uint4 gathers, x4 unroll, dual acc banks.
// STATS: 64-way spread-atomic sum/sumsq (tail ~#blocks/64 x 15ns).
template <int D, bool STATS, bool BIAS>
__global__ __launch_bounds__(256) void agg_kernel(const __half* __restrict__ Ut,
                                                  const int* __restrict__ csr,
                                                  const int* __restrict__ offs,
                                                  const float* __restrict__ deg,
                                                  const float* __restrict__ dinv,
                                                  const float* __restrict__ bias,
                                                  float* __restrict__ H,
                                                  double* __restrict__ tmp, int n) {
    constexpr int GPN = D / 8;
    constexpr int NPB = 256 / GPN;
    int g = threadIdx.x / GPN;
    int cl = threadIdx.x % GPN;
    int node = blockIdx.x * NPB + g;
    bool act = node < n;

    float a[8], b[8];
#pragma unroll
    for (int c = 0; c < 8; c++) { a[c] = 0.f; b[c] = 0.f; }

    int start = 0, cnt = 0;
    float dvi = 0.f;
    if (act) {
        start = offs[node];
        cnt = (int)deg[node] - 1;
        dvi = dinv[node];
        load8h(Ut + (size_t)node * D + cl * 8, a);   // self loop (pre-scaled)
    }
    const __half* __restrict__ base = Ut + cl * 8;
    int j = 0;
    for (; j + 4 <= cnt; j += 4) {
        int s0 = csr[start + j];
        int s1 = csr[start + j + 1];
        int s2 = csr[start + j + 2];
        int s3 = csr[start + j + 3];
        uint4 u0 = *(const uint4*)(base + (size_t)s0 * D);
        uint4 u1 = *(const uint4*)(base + (size_t)s1 * D);
        uint4 u2 = *(const uint4*)(base + (size_t)s2 * D);
        uint4 u3 = *(const uint4*)(base + (size_t)s3 * D);
        acc8h(u0, a);
        acc8h(u1, b);
        acc8h(u2, a);
        acc8h(u3, b);
    }
    if (j + 2 <= cnt) {
        int s0 = csr[start + j];
        int s1 = csr[start + j + 1];
        uint4 u0 = *(const uint4*)(base + (size_t)s0 * D);
        uint4 u1 = *(const uint4*)(base + (size_t)s1 * D);
        acc8h(u0, a);
        acc8h(u1, b);
        j += 2;
    }
    if (j < cnt) {
        int s0 = csr[start + j];
        uint4 u0 = *(const uint4*)(base + (size_t)s0 * D);
        acc8h(u0, a);
    }

    float h[8];
#pragma unroll
    for (int c = 0; c < 8; c++) h[c] = (a[c] + b[c]) * dvi;
    if (BIAS) {
#pragma unroll
        for (int c = 0; c < 8; c++) h[c] += bias[cl * 8 + c];
    }
    if (act) {
        float* dst = H + (size_t)node * D + cl * 8;
        *(float4*)dst = make_float4(h[0], h[1], h[2], h[3]);
        *(float4*)(dst + 4) = make_float4(h[4], h[5], h[6], h[7]);
    } else {
#pragma unroll
        for (int c = 0; c < 8; c++) h[c] = 0.f;   // no stats contribution
    }

    if (STATS) {
        float s[8], q[8];
#pragma unroll
        for (int c = 0; c < 8; c++) { s[c] = h[c]; q[c] = h[c] * h[c]; }
#pragma unroll
        for (int m = GPN; m < 64; m <<= 1) {
#pragma unroll
            for (int c = 0; c < 8; c++) {
                s[c] += __shfl_xor(s[c], m, 64);
                q[c] += __shfl_xor(q[c], m, 64);
            }
        }
        __shared__ float ps[4][GPN][8], pq[4][GPN][8];
        int wid = threadIdx.x >> 6;
        int lane = threadIdx.x & 63;
        if (lane < GPN) {
#pragma unroll
            for (int c = 0; c < 8; c++) { ps[wid][lane][c] = s[c]; pq[wid][lane][c] = q[c]; }
        }
        __syncthreads();
        if (threadIdx.x < D) {
            int cgi = threadIdx.x >> 3, ci = threadIdx.x & 7;
            float t1 = ps[0][cgi][ci] + ps[1][cgi][ci] + ps[2][cgi][ci] + ps[3][cgi][ci];
            float t2 = pq[0][cgi][ci] + pq[1][cgi][ci] + pq[2][cgi][ci] + pq[3][cgi][ci];
            int cp = (blockIdx.x & 63) * 2 * D;
            atomicAdd(&tmp[cp + threadIdx.x], (double)t1);
            atomicAdd(&tmp[cp + D + threadIdx.x], (double)t2);
        }
    }
}

// ---- register-blocked GEMM ----
// BNIN: scale/shift+GELU on staging. HALFOUT: fp16 out. STATS: spread atomics.
template <int DIN, int DOUT, bool BNIN, bool BIAS, bool DINVOUT, bool HALFOUT, bool STATS>
__global__ __launch_bounds__(256) void gemm_kernel(const float* __restrict__ Hin,
                                                   const float* __restrict__ W,
                                                   const float* __restrict__ scale,
                                                   const float* __restrict__ shift,
                                                   const float* __restrict__ bias,
                                                   const float* __restrict__ dinv,
                                                   float* __restrict__ Out,
                                                   double* __restrict__ tmp, int n) {
    constexpr int BNODES = 64;
    constexpr int KT = 32;
    constexpr int HP = DIN + 4;
    constexpr int VC = DOUT / 16;      // 8 (DOUT=128) or 4 (DOUT=64)
    constexpr int C4 = VC / 4;
    __shared__ float Hs[BNODES * HP];
    __shared__ float Ws[KT * DOUT];
    __shared__ float ps[STATS ? 4 : 1][16][VC];
    __shared__ float pq[STATS ? 4 : 1][16][VC];

    int node0 = blockIdx.x * BNODES;
    int nv = n - node0;
    if (nv > BNODES) nv = BNODES;
    int cg = threadIdx.x & 15;
    int ng = threadIdx.x >> 4;

    constexpr int F4 = BNODES * (DIN / 4);
    for (int f = threadIdx.x; f < F4; f += 256) {
        int nn = f / (DIN / 4);
        int k4 = f - nn * (DIN / 4);
        float4 v = make_float4(0.f, 0.f, 0.f, 0.f);
        if (nn < nv)
            v = *(const float4*)(Hin + (size_t)(node0 + nn) * DIN + k4 * 4);
        if (BNIN) {
            float4 sc = *(const float4*)(scale + k4 * 4);
            float4 sh = *(const float4*)(shift + k4 * 4);
            v.x = gelu_f(fmaf(v.x, sc.x, sh.x));
            v.y = gelu_f(fmaf(v.y, sc.y, sh.y));
            v.z = gelu_f(fmaf(v.z, sc.z, sh.z));
            v.w = gelu_f(fmaf(v.w, sc.w, sh.w));
        }
        *(float4*)(Hs + nn * HP + k4 * 4) = v;
    }

    float acc[4][VC];
#pragma unroll
    for (int i = 0; i < 4; i++)
#pragma unroll
        for (int c = 0; c < VC; c++) acc[i][c] = 0.0f;

    for (int kb = 0; kb < DIN; kb += KT) {
        __syncthreads();
        for (int f = threadIdx.x; f < KT * DOUT / 4; f += 256)
            *(float4*)(Ws + f * 4) = *(const float4*)(W + (size_t)kb * DOUT + f * 4);
        __syncthreads();
#pragma unroll
        for (int kk = 0; kk < KT; kk++) {
            float h[4];
#pragma unroll
            for (int i = 0; i < 4; i++)
                h[i] = Hs[(ng * 4 + i) * HP + kb + kk];
            float w[VC];
#pragma unroll
            for (int c = 0; c < C4; c++) {
                float4 w4 = *(const float4*)(Ws + kk * DOUT + cg * VC + c * 4);
                w[c * 4 + 0] = w4.x; w[c * 4 + 1] = w4.y;
                w[c * 4 + 2] = w4.z; w[c * 4 + 3] = w4.w;
            }
#pragma unroll
            for (int i = 0; i < 4; i++)
#pragma unroll
                for (int c = 0; c < VC; c++)
                    acc[i][c] = fmaf(h[i], w[c], acc[i][c]);
        }
    }

    float fin[4][VC];
#pragma unroll
    for (int i = 0; i < 4; i++) {
        int nn = ng * 4 + i;
        bool valid = nn < nv;
        int node = node0 + nn;
        float dv = 1.0f;
        if (DINVOUT && valid) dv = dinv[node];
#pragma unroll
        for (int c = 0; c < VC; c++) {
            float f = acc[i][c] * dv;
            if (BIAS) f += bias[cg * VC + c];
            fin[i][c] = valid ? f : 0.f;
        }
        if (valid) {
            if (HALFOUT) {
                __half* hp = (__half*)Out + (size_t)node * DOUT + cg * VC;
                if (VC == 8) {
                    __half2 pk[4];
                    pk[0] = __floats2half2_rn(fin[i][0], fin[i][1]);
                    pk[1] = __floats2half2_rn(fin[i][2], fin[i][3]);
                    pk[2] = __floats2half2_rn(fin[i][4], fin[i][5]);
                    pk[3] = __floats2half2_rn(fin[i][6], fin[i][7]);
                    *(uint4*)hp = *(uint4*)pk;
                } else {
                    __half2 pk[2];
                    pk[0] = __floats2half2_rn(fin[i][0], fin[i][1]);
                    pk[1] = __floats2half2_rn(fin[i][2], fin[i][3]);
                    *(uint2*)hp = *(uint2*)pk;
                }
            } else {
#pragma unroll
                for (int c = 0; c < C4; c++)
                    *(float4*)(Out + (size_t)node * DOUT + cg * VC + c * 4) =
                        make_float4(fin[i][c * 4 + 0], fin[i][c * 4 + 1],
                                    fin[i][c * 4 + 2], fin[i][c * 4 + 3]);
            }
        }
    }

    if (STATS) {
        float s[VC], q[VC];
#pragma unroll
        for (int c = 0; c < VC; c++) {
            s[c] = fin[0][c] + fin[1][c] + fin[2][c] + fin[3][c];
            q[c] = fin[0][c] * fin[0][c] + fin[1][c] * fin[1][c] +
                   fin[2][c] * fin[2][c] + fin[3][c] * fin[3][c];
        }
#pragma unroll
        for (int st = 16; st < 64; st <<= 1) {
#pragma unroll
            for (int c = 0; c < VC; c++) {
                s[c] += __shfl_xor(s[c], st, 64);
                q[c] += __shfl_xor(q[c], st, 64);
            }
        }
        int wid = threadIdx.x >> 6;
        int lane = threadIdx.x & 63;
        if (lane < 16) {
#pragma unroll
            for (int c = 0; c < VC; c++) { ps[wid][lane][c] = s[c]; pq[wid][lane][c] = q[c]; }
        }
        __syncthreads();
        if (threadIdx.x < DOUT) {
            int col = threadIdx.x;
            int cgi = col / VC, ci = col % VC;
            float t = ps[0][cgi][ci] + ps[1][cgi][ci] + ps[2][cgi][ci] + ps[3][cgi][ci];
            float t2 = pq[0][cgi][ci] + pq[1][cgi][ci] + pq[2][cgi][ci] + pq[3][cgi][ci];
            int cp = (blockIdx.x & 63) * 2 * DOUT;
            atomicAdd(&tmp[cp + col], (double)t);
            atomicAdd(&tmp[cp + DOUT + col], (double)t2);
        }
    }
}

// ---- fold 64 tmp copies -> per-channel scale/shift floats ----
template <int D>
__global__ void finalize_tmp_kernel(const double* __restrict__ tmp,
                                    const float* __restrict__ g, const float* __restrict__ be,
                                    float* __restrict__ scale, float* __restrict__ shift, int n) {
    int c = threadIdx.x;
    if (c < D) {
        double s = 0.0, q = 0.0;
        for (int gg = 0; gg < 64; gg++) {
            s += tmp[gg * 2 * D + c];
            q += tmp[gg * 2 * D + D + c];
        }
        double mu = s / n;
        double var = q / n - mu * mu;
        double inv = 1.0 / sqrt(var + 1e-5);
        double sc = (double)g[c] * inv;
        scale[c] = (float)sc;
        shift[c] = (float)((double)be[c] - mu * sc);
    }
}

// ---- fold 64 tmp copies -> raw stats sums (for norm_pool) ----
template <int D>
__global__ void combine_kernel(const double* __restrict__ tmp, double* __restrict__ stats) {
    int t = threadIdx.x;
    if (t < 2 * D) {
        double s = 0.0;
        for (int gg = 0; gg < 64; gg++) s += tmp[gg * 2 * D + t];
        stats[t] = s;
    }
}

// ---- layer-3: BN normalize + GELU + residual(x) + mean-pool accumulate ----
__global__ __launch_bounds__(256) void norm_pool_kernel(const float* __restrict__ X3,
                                                        const float* __restrict__ x0,
                                                        const double* __restrict__ stats,
                                                        const float* __restrict__ gw,
                                                        const float* __restrict__ be,
                                                        double* __restrict__ pool, int n) {
    constexpr int D = 64;
    constexpr int RPB = 4;
    int c = threadIdx.x % D;
    double mu = stats[c] / n;
    double var = stats[c + D] / n - mu * mu;
    double inv = 1.0 / sqrt(var + 1e-5);
    float scale = (float)((double)gw[c] * inv);
    float shift = (float)((double)be[c] - mu * (double)gw[c] * inv);
    int r0 = threadIdx.x / D;
    int rowsPerGrid = gridDim.x * RPB;
    double s = 0.0;
    for (int r = blockIdx.x * RPB + r0; r < n; r += rowsPerGrid) {
        size_t idx = (size_t)r * D + c;
        float t = fmaf(X3[idx], scale, shift);
        float res = x0[idx] + gelu_f(t);
        s += res;
    }
    __shared__ double sh[256];
    sh[threadIdx.x] = s;
    __syncthreads();
    if (threadIdx.x < D) {
#pragma unroll
        for (int j = 1; j < RPB; j++) s += sh[threadIdx.x + j * D];
        atomicAdd(&pool[c], s);
    }
}

// ---- head MLP: 64 ->128 ->64 ->32 ->1, single block ----
__global__ __launch_bounds__(128) void mlp_kernel(const double* __restrict__ pool,
                                                  const float* __restrict__ w1, const float* __restrict__ b1,
                                                  const float* __restrict__ w2, const float* __restrict__ b2,
                                                  const float* __restrict__ w3, const float* __restrict__ b3,
                                                  const float* __restrict__ w4, const float* __restrict__ b4,
                                                  float* __restrict__ out, int n) {
    __shared__ float v0[64], h1[128], h2[64], h3[32];
    int t = threadIdx.x;
    if (t < 64) v0[t] = (float)(pool[t] / (double)n);
    __syncthreads();
    if (t < 128) {
        float a = b1[t];
        for (int k = 0; k < 64; k++) a = fmaf(v0[k], w1[k * 128 + t], a);
        h1[t] = gelu_f(a);
    }
    __syncthreads();
    if (t < 64) {
        float a = b2[t];
        for (int k = 0; k < 128; k++) a = fmaf(h1[k], w2[k * 64 + t], a);
        h2[t] = gelu_f(a);
    }
    __syncthreads();
    if (t < 32) {
        float a = b3[t];
        for (int k = 0; k < 64; k++) a = fmaf(h2[k], w3[k * 32 + t], a);
        h3[t] = gelu_f(a);
    }
    __syncthreads();
    if (t == 0) {
        float a = b4[0];
        for (int k = 0; k < 32; k++) a = fmaf(h3[k], w4[k], a);
        out[0] = a;
    }
}

extern "C" void kernel_launch(void* const* d_in, const int* in_sizes, int n_in,
                              void* d_out, int out_size, void* d_ws, size_t ws_size,
                              hipStream_t stream) {
    const float* x    = (const float*)d_in[0];
    const int*   ei   = (const int*)d_in[1];
    const float* W1   = (const float*)d_in[2];
    const float* b1   = (const float*)d_in[3];
    const float* g1   = (const float*)d_in[4];
    const float* be1  = (const float*)d_in[5];
    const float* W2   = (const float*)d_in[6];
    const float* b2   = (const float*)d_in[7];
    const float* g2   = (const float*)d_in[8];
    const float* be2  = (const float*)d_in[9];
    const float* W3   = (const float*)d_in[10];
    const float* b3   = (const float*)d_in[11];
    const float* g3   = (const float*)d_in[12];
    const float* be3  = (const float*)d_in[13];
    const float* fc1w = (const float*)d_in[14];
    const float* fc1b = (const float*)d_in[15];
    const float* fc2w = (const float*)d_in[16];
    const float* fc2b = (const float*)d_in[17];
    const float* fc3w = (const float*)d_in[18];
    const float* fc3b = (const float*)d_in[19];
    const float* fc4w = (const float*)d_in[20];
    const float* fc4b = (const float*)d_in[21];

    const int N = in_sizes[0] / 64;
    const int E = in_sizes[1] / 2;
    const int* e_row = ei;       // source
    const int* e_col = ei + E;   // target (aggregation index)

    // ---- workspace layout (~105 MB) ----
    char* ws = (char*)d_ws;
    size_t off = 0;
    double* pool   = (double*)(ws + off); off += 64 * sizeof(double);
    double* tmp1   = (double*)(ws + off); off += 64 * 256 * sizeof(double);  // gemm1 stats spread
    double* tmp2   = (double*)(ws + off); off += 64 * 256 * sizeof(double);  // agg2 stats spread
    double* tmp3   = (double*)(ws + off); off += 64 * 128 * sizeof(double);  // agg3 stats spread
    double* stats3 = (double*)(ws + off); off += 128 * sizeof(double);
    const int NDBL = 64 + 64 * 256 * 2 + 64 * 128 + 128;  // zeroed by init
    float* scale1 = (float*)(ws + off); off += 128 * sizeof(float);
    float* shift1 = (float*)(ws + off); off += 128 * sizeof(float);
    float* scale2 = (float*)(ws + off); off += 128 * sizeof(float);
    float* shift2 = (float*)(ws + off); off += 128 * sizeof(float);
    float* deg   = (float*)(ws + off); off += (size_t)N * sizeof(float);
    float* dinv  = (float*)(ws + off); off += (size_t)N * sizeof(float);
    off = (off + 15) & ~(size_t)15;
    int* offs    = (int*)(ws + off); off += (size_t)N * sizeof(int);
    int* cursor  = (int*)(ws + off); off += (size_t)N * sizeof(int);
    int* bsums   = (int*)(ws + off); off += 512 * sizeof(int);
    int* csr     = (int*)(ws + off); off += (size_t)E * sizeof(int);
    off = (off + 255) & ~(size_t)255;
    __half* Ut   = (__half*)(ws + off); off += (size_t)N * 128 * sizeof(__half);  // fp16 gather table
    float* A1    = (float*)(ws + off);  off += (size_t)N * 64 * sizeof(float);    // agg1 out (fp32)
    float* H     = (float*)(ws + off);  off += (size_t)N * 128 * sizeof(float);   // fp32 row-major
    __half* xh   = Ut;  // alias: xh dead after agg1, before gemm2 writes Ut

    const int nb256 = (N + 255) / 256;
    const int ebl = (E + 255) / 256;

    init_kernel<<<nb256, 256, 0, stream>>>(deg, pool, N, NDBL);
    degree_kernel<<<ebl, 256, 0, stream>>>(e_col, deg, E);
    scan1_kernel<<<nb256, 256, 0, stream>>>(deg, dinv, offs, bsums, N);
    scan2_kernel<<<1, 512, 0, stream>>>(bsums, nb256);
    scan3_kernel<<<nb256, 256, 0, stream>>>(offs, bsums, cursor, N);
    fill_kernel<<<ebl, 256, 0, stream>>>(e_row, e_col, cursor, csr, E);

    // Layer 1: x -> fp16 (dinv-scaled); agg 64-dim -> A1; GEMM(+b1,+stats->tmp1) -> H1
    halfconv_kernel<<<(N * 8 + 255) / 256, 256, 0, stream>>>(x, dinv, xh, N);
    agg_kernel<64, false, false><<<(N + 31) / 32, 256, 0, stream>>>(
        xh, csr, offs, deg, dinv, nullptr, A1, nullptr, N);
    gemm_kernel<64, 128, false, true, false, false, true><<<(N + 63) / 64, 256, 0, stream>>>(
        A1, W1, nullptr, nullptr, b1, dinv, H, tmp1, N);
    finalize_tmp_kernel<128><<<1, 128, 0, stream>>>(tmp1, g1, be1, scale1, shift1, N);

    // Layer 2: GEMM (BN1+GELU fused, dinv prescale, fp16 out) -> Ut; agg(+b2,+stats->tmp2) -> H2
    gemm_kernel<128, 128, true, false, true, true, false><<<(N + 63) / 64, 256, 0, stream>>>(
        H, W2, scale1, shift1, nullptr, dinv, (float*)Ut, nullptr, N);
    agg_kernel<128, true, true><<<(N + 15) / 16, 256, 0, stream>>>(
        Ut, csr, offs, deg, dinv, b2, H, tmp2, N);
    finalize_tmp_kernel<128><<<1, 128, 0, stream>>>(tmp2, g2, be2, scale2, shift2, N);

    // Layer 3: GEMM (BN2+GELU fused, dinv prescale, fp16 out 64) -> Ut; agg(+b3,+stats->tmp3) -> H3
    gemm_kernel<128, 64, true, false, true, true, false><<<(N + 63) / 64, 256, 0, stream>>>(
        H, W3, scale2, shift2, nullptr, dinv, (float*)Ut, nullptr, N);
    agg_kernel<64, true, true><<<(N + 31) / 32, 256, 0, stream>>>(
        Ut, csr, offs, deg, dinv, b3, H, tmp3, N);
    combine_kernel<64><<<1, 128, 0, stream>>>(tmp3, stats3);

    // Epilogue: BN3+GELU+residual+meanpool, then head MLP
    norm_pool_kernel<<<1024, 256, 0, stream>>>(H, x, stats3, g3, be3, pool, N);
    mlp_kernel<<<1, 128, 0, stream>>>(pool, fc1w, fc1b, fc2w, fc2b, fc3w, fc3b,
                                      fc4w, fc4b, (float*)d_out, N);
}

// Round 13
// 471.618 us; speedup vs baseline: 2.0138x; 1.1930x over previous
//
#include <hip/hip_runtime.h>
#include <hip/hip_bf16.h>
#include <hip/hip_fp16.h>
#include <math.h>

// GNN: 3-layer GCN + BN + GELU + residual + meanpool + MLP -> scalar.
// R13 = R12 content, compile-fixed: STATS epilogues are `if constexpr` with
// shared scratch declared inside (clang 22 hard-errors on the OOB constant
// index in the type-checked-but-dead runtime-if branch when STATS=false).
// R12 plan: LDS-binned two-pass CSR build replacing fill_kernel (129us,
// 105MB write-amp). Pass 1: per-block LDS histogram over 391 buckets,
// ONE global atomic per (block,bucket), line-coalesced packed runs.
// Pass 2: per-bucket LDS-cursor placement. agg/gemm/stats = R11.

__device__ __forceinline__ float gelu_f(float x) {
    return 0.5f * x * (1.0f + erff(x * 0.7071067811865476f));
}

__device__ __forceinline__ int wave_incl_scan(int v, int lane) {
#pragma unroll
    for (int off = 1; off < 64; off <<= 1) {
        int t = __shfl_up(v, (unsigned)off, 64);
        if (lane >= off) v += t;
    }
    return v;
}

__device__ __forceinline__ void load8h(const __half* __restrict__ p, float* f) {
    uint4 u = *(const uint4*)p;
    const __half2* h2p = (const __half2*)&u;
#pragma unroll
    for (int i = 0; i < 4; i++) {
        float2 t = __half22float2(h2p[i]);
        f[2 * i] = t.x;
        f[2 * i + 1] = t.y;
    }
}

__device__ __forceinline__ void acc8h(const uint4& u, float* f) {
    const __half2* h2p = (const __half2*)&u;
#pragma unroll
    for (int i = 0; i < 4; i++) {
        float2 t = __half22float2(h2p[i]);
        f[2 * i] += t.x;
        f[2 * i + 1] += t.y;
    }
}

// ---- init: deg = 1.0 (self loop), zero double accumulators ----
__global__ void init_kernel(float* __restrict__ deg, double* __restrict__ dbls,
                            int n, int ndbl) {
    int i = blockIdx.x * 256 + threadIdx.x;
    if (i < n) deg[i] = 1.0f;
    if (i < ndbl) dbls[i] = 0.0;
}

__global__ void degree_kernel(const int* __restrict__ col, float* __restrict__ deg, int E) {
    int e = blockIdx.x * 256 + threadIdx.x;
    if (e < E) atomicAdd(&deg[col[e]], 1.0f);
}

__global__ __launch_bounds__(256) void scan1_kernel(const float* __restrict__ deg,
                                                    float* __restrict__ dinv,
                                                    int* __restrict__ offs,
                                                    int* __restrict__ bsums, int n) {
    int i = blockIdx.x * 256 + threadIdx.x;
    int lane = threadIdx.x & 63;
    int wid = threadIdx.x >> 6;
    int cnt = 0;
    if (i < n) {
        float d = deg[i];
        dinv[i] = 1.0f / sqrtf(d);
        cnt = (int)d - 1;
    }
    int incl = wave_incl_scan(cnt, lane);
    __shared__ int ws[4];
    if (lane == 63) ws[wid] = incl;
    __syncthreads();
    if (threadIdx.x == 0) {
        int a = 0;
#pragma unroll
        for (int j = 0; j < 4; j++) { int t = ws[j]; ws[j] = a; a += t; }
        bsums[blockIdx.x] = a;
    }
    __syncthreads();
    int excl = incl - cnt + ws[wid];
    if (i < n) offs[i] = excl;
}

__global__ __launch_bounds__(512) void scan2_kernel(int* __restrict__ bsums, int nblk) {
    int lane = threadIdx.x & 63;
    int wid = threadIdx.x >> 6;
    int v = (threadIdx.x < nblk) ? bsums[threadIdx.x] : 0;
    int incl = wave_incl_scan(v, lane);
    __shared__ int ws[8];
    if (lane == 63) ws[wid] = incl;
    __syncthreads();
    if (threadIdx.x == 0) {
        int a = 0;
#pragma unroll
        for (int j = 0; j < 8; j++) { int t = ws[j]; ws[j] = a; a += t; }
    }
    __syncthreads();
    int excl = incl - v + ws[wid];
    if (threadIdx.x < nblk) bsums[threadIdx.x] = excl;
}

// scan3: finalize offs; init bucket cursors (bucket = 256 nodes)
__global__ void scan3_kernel(int* __restrict__ offs, const int* __restrict__ bsums,
                             int* __restrict__ bcur, int n) {
    int i = blockIdx.x * 256 + threadIdx.x;
    if (i < n) {
        int o = offs[i] + bsums[i >> 8];
        offs[i] = o;
        if ((i & 255) == 0) bcur[i >> 8] = o;
    }
}

// ---- CSR pass 1: LDS-binned stage. One global atomic per (block,bucket). ----
#define EPB 8192
__global__ __launch_bounds__(512) void binstage_kernel(const int* __restrict__ row,
                                                       const int* __restrict__ col,
                                                       int* __restrict__ bcur,
                                                       unsigned int* __restrict__ stage,
                                                       int E, int nbuckets) {
    __shared__ int cnt[512];
    __shared__ int gbase[512];
    int e0 = blockIdx.x * EPB;
    int eend = e0 + EPB;
    if (eend > E) eend = E;
    for (int b = threadIdx.x; b < nbuckets; b += 512) cnt[b] = 0;
    __syncthreads();
    for (int e = e0 + threadIdx.x; e < eend; e += 512)
        atomicAdd(&cnt[col[e] >> 8], 1);
    __syncthreads();
    for (int b = threadIdx.x; b < nbuckets; b += 512) {
        int c = cnt[b];
        gbase[b] = c ? atomicAdd(&bcur[b], c) : 0;
        cnt[b] = 0;  // reuse as local cursor
    }
    __syncthreads();
    for (int e = e0 + threadIdx.x; e < eend; e += 512) {
        int c = col[e];
        int b = c >> 8;
        int lp = atomicAdd(&cnt[b], 1);
        stage[gbase[b] + lp] = ((unsigned int)row[e] << 8) | (unsigned int)(c & 255);
    }
}

// ---- CSR pass 2: one block per bucket, LDS cursors -> exact csr ----
__global__ __launch_bounds__(256) void bucket_sort_kernel(const unsigned int* __restrict__ stage,
                                                          const int* __restrict__ offs,
                                                          int* __restrict__ csr, int N, int E) {
    __shared__ int cur[256];
    int b = blockIdx.x;
    int nb0 = b << 8;
    int base = offs[nb0];
    int nend = nb0 + 256;
    int end = (nend < N) ? offs[nend] : E;
    {
        int node = nb0 + threadIdx.x;
        cur[threadIdx.x] = (node < N) ? (offs[node] - base) : 0;
    }
    __syncthreads();
    int cnt = end - base;
    for (int t = threadIdx.x; t < cnt; t += 256) {
        unsigned int v = stage[base + t];
        int lc = v & 255;
        int src = (int)(v >> 8);
        int pos = atomicAdd(&cur[lc], 1);
        csr[base + pos] = src;
    }
}

// ---- convert x[N][64] fp32 -> xh[N][64] fp16, scaled by dinv[node] ----
__global__ __launch_bounds__(256) void halfconv_kernel(const float* __restrict__ x,
                                                       const float* __restrict__ dinv,
                                                       __half* __restrict__ xh, int N) {
    int t = blockIdx.x * 256 + threadIdx.x;   // one 8-float chunk per thread
    if (t >= N * 8) return;
    int node = t >> 3;
    float dv = dinv[node];
    const float4* p = (const float4*)(x + (size_t)t * 8);
    float4 a = p[0], b = p[1];
    __half2 h[4];
    h[0] = __floats2half2_rn(a.x * dv, a.y * dv);
    h[1] = __floats2half2_rn(a.z * dv, a.w * dv);
    h[2] = __floats2half2_rn(b.x * dv, b.y * dv);
    h[3] = __floats2half2_rn(b.z * dv, b.w * dv);
    *(uint4*)(xh + (size_t)t * 8) = *(uint4*)h;
}

// ---- aggregation: H[i][D] = dinv_i*(Ut[i] + sum in-edge Ut[src]) (+bias) ----
// Ut fp16 row-major, pre-scaled by dinv[src]; fp32 accumulate.
// GPN = D/8 lanes per node, 16B uint4 gathers, x4 unroll, dual acc banks.
template <int D, bool STATS, bool BIAS>
__global__ __launch_bounds__(256) void agg_kernel(const __half* __restrict__ Ut,
                                                  const int* __restrict__ csr,
                                                  const int* __restrict__ offs,
                                                  const float* __restrict__ deg,
                                                  const float* __restrict__ dinv,
                                                  const float* __restrict__ bias,
                                                  float* __restrict__ H,
                                                  double* __restrict__ tmp, int n) {
    constexpr int GPN = D / 8;
    constexpr int NPB = 256 / GPN;
    int g = threadIdx.x / GPN;
    int cl = threadIdx.x % GPN;
    int node = blockIdx.x * NPB + g;
    bool act = node < n;

    float a[8], b[8];
#pragma unroll
    for (int c = 0; c < 8; c++) { a[c] = 0.f; b[c] = 0.f; }

    int start = 0, cnt = 0;
    float dvi = 0.f;
    if (act) {
        start = offs[node];
        cnt = (int)deg[node] - 1;
        dvi = dinv[node];
        load8h(Ut + (size_t)node * D + cl * 8, a);   // self loop (pre-scaled)
    }
    const __half* __restrict__ base = Ut + cl * 8;
    int j = 0;
    for (; j + 4 <= cnt; j += 4) {
        int s0 = csr[start + j];
        int s1 = csr[start + j + 1];
        int s2 = csr[start + j + 2];
        int s3 = csr[start + j + 3];
        uint4 u0 = *(const uint4*)(base + (size_t)s0 * D);
        uint4 u1 = *(const uint4*)(base + (size_t)s1 * D);
        uint4 u2 = *(const uint4*)(base + (size_t)s2 * D);
        uint4 u3 = *(const uint4*)(base + (size_t)s3 * D);
        acc8h(u0, a);
        acc8h(u1, b);
        acc8h(u2, a);
        acc8h(u3, b);
    }
    if (j + 2 <= cnt) {
        int s0 = csr[start + j];
        int s1 = csr[start + j + 1];
        uint4 u0 = *(const uint4*)(base + (size_t)s0 * D);
        uint4 u1 = *(const uint4*)(base + (size_t)s1 * D);
        acc8h(u0, a);
        acc8h(u1, b);
        j += 2;
    }
    if (j < cnt) {
        int s0 = csr[start + j];
        uint4 u0 = *(const uint4*)(base + (size_t)s0 * D);
        acc8h(u0, a);
    }

    float h[8];
#pragma unroll
    for (int c = 0; c < 8; c++) h[c] = (a[c] + b[c]) * dvi;
    if (BIAS) {
#pragma unroll
        for (int c = 0; c < 8; c++) h[c] += bias[cl * 8 + c];
    }
    if (act) {
        float* dst = H + (size_t)node * D + cl * 8;
        *(float4*)dst = make_float4(h[0], h[1], h[2], h[3]);
        *(float4*)(dst + 4) = make_float4(h[4], h[5], h[6], h[7]);
    } else {
#pragma unroll
        for (int c = 0; c < 8; c++) h[c] = 0.f;   // no stats contribution
    }

    if constexpr (STATS) {
        float s[8], q[8];
#pragma unroll
        for (int c = 0; c < 8; c++) { s[c] = h[c]; q[c] = h[c] * h[c]; }
#pragma unroll
        for (int m = GPN; m < 64; m <<= 1) {
#pragma unroll
            for (int c = 0; c < 8; c++) {
                s[c] += __shfl_xor(s[c], m, 64);
                q[c] += __shfl_xor(q[c], m, 64);
            }
        }
        __shared__ float ps[4][GPN][8], pq[4][GPN][8];
        int wid = threadIdx.x >> 6;
        int lane = threadIdx.x & 63;
        if (lane < GPN) {
#pragma unroll
            for (int c = 0; c < 8; c++) { ps[wid][lane][c] = s[c]; pq[wid][lane][c] = q[c]; }
        }
        __syncthreads();
        if (threadIdx.x < D) {
            int cgi = threadIdx.x >> 3, ci = threadIdx.x & 7;
            float t1 = ps[0][cgi][ci] + ps[1][cgi][ci] + ps[2][cgi][ci] + ps[3][cgi][ci];
            float t2 = pq[0][cgi][ci] + pq[1][cgi][ci] + pq[2][cgi][ci] + pq[3][cgi][ci];
            int cp = (blockIdx.x & 63) * 2 * D;
            atomicAdd(&tmp[cp + threadIdx.x], (double)t1);
            atomicAdd(&tmp[cp + D + threadIdx.x], (double)t2);
        }
    }
}

// ---- register-blocked GEMM ----
// BNIN: scale/shift+GELU on staging. HALFOUT: fp16 out. STATS: spread atomics.
template <int DIN, int DOUT, bool BNIN, bool BIAS, bool DINVOUT, bool HALFOUT, bool STATS>
__global__ __launch_bounds__(256) void gemm_kernel(const float* __restrict__ Hin,
                                                   const float* __restrict__ W,
                                                   const float* __restrict__ scale,
                                                   const float* __restrict__ shift,
                                                   const float* __restrict__ bias,
                                                   const float* __restrict__ dinv,
                                                   float* __restrict__ Out,
                                                   double* __restrict__ tmp, int n) {
    constexpr int BNODES = 64;
    constexpr int KT = 32;
    constexpr int HP = DIN + 4;
    constexpr int VC = DOUT / 16;      // 8 (DOUT=128) or 4 (DOUT=64)
    constexpr int C4 = VC / 4;
    __shared__ float Hs[BNODES * HP];
    __shared__ float Ws[KT * DOUT];

    int node0 = blockIdx.x * BNODES;
    int nv = n - node0;
    if (nv > BNODES) nv = BNODES;
    int cg = threadIdx.x & 15;
    int ng = threadIdx.x >> 4;

    constexpr int F4 = BNODES * (DIN / 4);
    for (int f = threadIdx.x; f < F4; f += 256) {
        int nn = f / (DIN / 4);
        int k4 = f - nn * (DIN / 4);
        float4 v = make_float4(0.f, 0.f, 0.f, 0.f);
        if (nn < nv)
            v = *(const float4*)(Hin + (size_t)(node0 + nn) * DIN + k4 * 4);
        if (BNIN) {
            float4 sc = *(const float4*)(scale + k4 * 4);
            float4 sh = *(const float4*)(shift + k4 * 4);
            v.x = gelu_f(fmaf(v.x, sc.x, sh.x));
            v.y = gelu_f(fmaf(v.y, sc.y, sh.y));
            v.z = gelu_f(fmaf(v.z, sc.z, sh.z));
            v.w = gelu_f(fmaf(v.w, sc.w, sh.w));
        }
        *(float4*)(Hs + nn * HP + k4 * 4) = v;
    }

    float acc[4][VC];
#pragma unroll
    for (int i = 0; i < 4; i++)
#pragma unroll
        for (int c = 0; c < VC; c++) acc[i][c] = 0.0f;

    for (int kb = 0; kb < DIN; kb += KT) {
        __syncthreads();
        for (int f = threadIdx.x; f < KT * DOUT / 4; f += 256)
            *(float4*)(Ws + f * 4) = *(const float4*)(W + (size_t)kb * DOUT + f * 4);
        __syncthreads();
#pragma unroll
        for (int kk = 0; kk < KT; kk++) {
            float h[4];
#pragma unroll
            for (int i = 0; i < 4; i++)
                h[i] = Hs[(ng * 4 + i) * HP + kb + kk];
            float w[VC];
#pragma unroll
            for (int c = 0; c < C4; c++) {
                float4 w4 = *(const float4*)(Ws + kk * DOUT + cg * VC + c * 4);
                w[c * 4 + 0] = w4.x; w[c * 4 + 1] = w4.y;
                w[c * 4 + 2] = w4.z; w[c * 4 + 3] = w4.w;
            }
#pragma unroll
            for (int i = 0; i < 4; i++)
#pragma unroll
                for (int c = 0; c < VC; c++)
                    acc[i][c] = fmaf(h[i], w[c], acc[i][c]);
        }
    }

    float fin[4][VC];
#pragma unroll
    for (int i = 0; i < 4; i++) {
        int nn = ng * 4 + i;
        bool valid = nn < nv;
        int node = node0 + nn;
        float dv = 1.0f;
        if (DINVOUT && valid) dv = dinv[node];
#pragma unroll
        for (int c = 0; c < VC; c++) {
            float f = acc[i][c] * dv;
            if (BIAS) f += bias[cg * VC + c];
            fin[i][c] = valid ? f : 0.f;
        }
        if (valid) {
            if (HALFOUT) {
                __half* hp = (__half*)Out + (size_t)node * DOUT + cg * VC;
                if (VC == 8) {
                    __half2 pk[4];
                    pk[0] = __floats2half2_rn(fin[i][0], fin[i][1]);
                    pk[1] = __floats2half2_rn(fin[i][2], fin[i][3]);
                    pk[2] = __floats2half2_rn(fin[i][4], fin[i][5]);
                    pk[3] = __floats2half2_rn(fin[i][6], fin[i][7]);
                    *(uint4*)hp = *(uint4*)pk;
                } else {
                    __half2 pk[2];
                    pk[0] = __floats2half2_rn(fin[i][0], fin[i][1]);
                    pk[1] = __floats2half2_rn(fin[i][2], fin[i][3]);
                    *(uint2*)hp = *(uint2*)pk;
                }
            } else {
#pragma unroll
                for (int c = 0; c < C4; c++)
                    *(float4*)(Out + (size_t)node * DOUT + cg * VC + c * 4) =
                        make_float4(fin[i][c * 4 + 0], fin[i][c * 4 + 1],
                                    fin[i][c * 4 + 2], fin[i][c * 4 + 3]);
            }
        }
    }

    if constexpr (STATS) {
        __shared__ float ps[4][16][VC];
        __shared__ float pq[4][16][VC];
        float s[VC], q[VC];
#pragma unroll
        for (int c = 0; c < VC; c++) {
            s[c] = fin[0][c] + fin[1][c] + fin[2][c] + fin[3][c];
            q[c] = fin[0][c] * fin[0][c] + fin[1][c] * fin[1][c] +
                   fin[2][c] * fin[2][c] + fin[3][c] * fin[3][c];
        }
#pragma unroll
        for (int st = 16; st < 64; st <<= 1) {
#pragma unroll
            for (int c = 0; c < VC; c++) {
                s[c] += __shfl_xor(s[c], st, 64);
                q[c] += __shfl_xor(q[c], st, 64);
            }
        }
        int wid = threadIdx.x >> 6;
        int lane = threadIdx.x & 63;
        if (lane < 16) {
#pragma unroll
            for (int c = 0; c < VC; c++) { ps[wid][lane][c] = s[c]; pq[wid][lane][c] = q[c]; }
        }
        __syncthreads();
        if (threadIdx.x < DOUT) {
            int col = threadIdx.x;
            int cgi = col / VC, ci = col % VC;
            float t = ps[0][cgi][ci] + ps[1][cgi][ci] + ps[2][cgi][ci] + ps[3][cgi][ci];
            float t2 = pq[0][cgi][ci] + pq[1][cgi][ci] + pq[2][cgi][ci] + pq[3][cgi][ci];
            int cp = (blockIdx.x & 63) * 2 * DOUT;
            atomicAdd(&tmp[cp + col], (double)t);
            atomicAdd(&tmp[cp + DOUT + col], (double)t2);
        }
    }
}

// ---- fold 64 tmp copies -> per-channel scale/shift floats ----
template <int D>
__global__ void finalize_tmp_kernel(const double* __restrict__ tmp,
                                    const float* __restrict__ g, const float* __restrict__ be,
                                    float* __restrict__ scale, float* __restrict__ shift, int n) {
    int c = threadIdx.x;
    if (c < D) {
        double s = 0.0, q = 0.0;
        for (int gg = 0; gg < 64; gg++) {
            s += tmp[gg * 2 * D + c];
            q += tmp[gg * 2 * D + D + c];
        }
        double mu = s / n;
        double var = q / n - mu * mu;
        double inv = 1.0 / sqrt(var + 1e-5);
        double sc = (double)g[c] * inv;
        scale[c] = (float)sc;
        shift[c] = (float)((double)be[c] - mu * sc);
    }
}

// ---- fold 64 tmp copies -> raw stats sums (for norm_pool) ----
template <int D>
__global__ void combine_kernel(const double* __restrict__ tmp, double* __restrict__ stats) {
    int t = threadIdx.x;
    if (t < 2 * D) {
        double s = 0.0;
        for (int gg = 0; gg < 64; gg++) s += tmp[gg * 2 * D + t];
        stats[t] = s;
    }
}

// ---- layer-3: BN normalize + GELU + residual(x) + mean-pool accumulate ----
__global__ __launch_bounds__(256) void norm_pool_kernel(const float* __restrict__ X3,
                                                        const float* __restrict__ x0,
                                                        const double* __restrict__ stats,
                                                        const float* __restrict__ gw,
                                                        const float* __restrict__ be,
                                                        double* __restrict__ pool, int n) {
    constexpr int D = 64;
    constexpr int RPB = 4;
    int c = threadIdx.x % D;
    double mu = stats[c] / n;
    double var = stats[c + D] / n - mu * mu;
    double inv = 1.0 / sqrt(var + 1e-5);
    float scale = (float)((double)gw[c] * inv);
    float shift = (float)((double)be[c] - mu * (double)gw[c] * inv);
    int r0 = threadIdx.x / D;
    int rowsPerGrid = gridDim.x * RPB;
    double s = 0.0;
    for (int r = blockIdx.x * RPB + r0; r < n; r += rowsPerGrid) {
        size_t idx = (size_t)r * D + c;
        float t = fmaf(X3[idx], scale, shift);
        float res = x0[idx] + gelu_f(t);
        s += res;
    }
    __shared__ double sh[256];
    sh[threadIdx.x] = s;
    __syncthreads();
    if (threadIdx.x < D) {
#pragma unroll
        for (int j = 1; j < RPB; j++) s += sh[threadIdx.x + j * D];
        atomicAdd(&pool[c], s);
    }
}

// ---- head MLP: 64 ->128 ->64 ->32 ->1, single block ----
__global__ __launch_bounds__(128) void mlp_kernel(const double* __restrict__ pool,
                                                  const float* __restrict__ w1, const float* __restrict__ b1,
                                                  const float* __restrict__ w2, const float* __restrict__ b2,
                                                  const float* __restrict__ w3, const float* __restrict__ b3,
                                                  const float* __restrict__ w4, const float* __restrict__ b4,
                                                  float* __restrict__ out, int n) {
    __shared__ float v0[64], h1[128], h2[64], h3[32];
    int t = threadIdx.x;
    if (t < 64) v0[t] = (float)(pool[t] / (double)n);
    __syncthreads();
    if (t < 128) {
        float a = b1[t];
        for (int k = 0; k < 64; k++) a = fmaf(v0[k], w1[k * 128 + t], a);
        h1[t] = gelu_f(a);
    }
    __syncthreads();
    if (t < 64) {
        float a = b2[t];
        for (int k = 0; k < 128; k++) a = fmaf(h1[k], w2[k * 64 + t], a);
        h2[t] = gelu_f(a);
    }
    __syncthreads();
    if (t < 32) {
        float a = b3[t];
        for (int k = 0; k < 64; k++) a = fmaf(h2[k], w3[k * 32 + t], a);
        h3[t] = gelu_f(a);
    }
    __syncthreads();
    if (t == 0) {
        float a = b4[0];
        for (int k = 0; k < 32; k++) a = fmaf(h3[k], w4[k], a);
        out[0] = a;
    }
}

extern "C" void kernel_launch(void* const* d_in, const int* in_sizes, int n_in,
                              void* d_out, int out_size, void* d_ws, size_t ws_size,
                              hipStream_t stream) {
    const float* x    = (const float*)d_in[0];
    const int*   ei   = (const int*)d_in[1];
    const float* W1   = (const float*)d_in[2];
    const float* b1   = (const float*)d_in[3];
    const float* g1   = (const float*)d_in[4];
    const float* be1  = (const float*)d_in[5];
    const float* W2   = (const float*)d_in[6];
    const float* b2   = (const float*)d_in[7];
    const float* g2   = (const float*)d_in[8];
    const float* be2  = (const float*)d_in[9];
    const float* W3   = (const float*)d_in[10];
    const float* b3   = (const float*)d_in[11];
    const float* g3   = (const float*)d_in[12];
    const float* be3  = (const float*)d_in[13];
    const float* fc1w = (const float*)d_in[14];
    const float* fc1b = (const float*)d_in[15];
    const float* fc2w = (const float*)d_in[16];
    const float* fc2b = (const float*)d_in[17];
    const float* fc3w = (const float*)d_in[18];
    const float* fc3b = (const float*)d_in[19];
    const float* fc4w = (const float*)d_in[20];
    const float* fc4b = (const float*)d_in[21];

    const int N = in_sizes[0] / 64;
    const int E = in_sizes[1] / 2;
    const int* e_row = ei;       // source
    const int* e_col = ei + E;   // target (aggregation index)
    const int nbuckets = (N + 255) >> 8;

    // ---- workspace layout (~112 MB) ----
    char* ws = (char*)d_ws;
    size_t off = 0;
    double* pool   = (double*)(ws + off); off += 64 * sizeof(double);
    double* tmp1   = (double*)(ws + off); off += 64 * 256 * sizeof(double);  // gemm1 stats spread
    double* tmp2   = (double*)(ws + off); off += 64 * 256 * sizeof(double);  // agg2 stats spread
    double* tmp3   = (double*)(ws + off); off += 64 * 128 * sizeof(double);  // agg3 stats spread
    double* stats3 = (double*)(ws + off); off += 128 * sizeof(double);
    const int NDBL = 64 + 64 * 256 * 2 + 64 * 128 + 128;  // zeroed by init
    float* scale1 = (float*)(ws + off); off += 128 * sizeof(float);
    float* shift1 = (float*)(ws + off); off += 128 * sizeof(float);
    float* scale2 = (float*)(ws + off); off += 128 * sizeof(float);
    float* shift2 = (float*)(ws + off); off += 128 * sizeof(float);
    float* deg   = (float*)(ws + off); off += (size_t)N * sizeof(float);
    float* dinv  = (float*)(ws + off); off += (size_t)N * sizeof(float);
    off = (off + 15) & ~(size_t)15;
    int* offs    = (int*)(ws + off); off += (size_t)N * sizeof(int);
    int* bcur    = (int*)(ws + off); off += 512 * sizeof(int);
    int* bsums   = (int*)(ws + off); off += 512 * sizeof(int);
    int* csr     = (int*)(ws + off); off += (size_t)E * sizeof(int);
    unsigned int* stage = (unsigned int*)(ws + off); off += (size_t)E * sizeof(unsigned int);
    off = (off + 255) & ~(size_t)255;
    __half* Ut   = (__half*)(ws + off); off += (size_t)N * 128 * sizeof(__half);  // fp16 gather table
    float* A1    = (float*)(ws + off);  off += (size_t)N * 64 * sizeof(float);    // agg1 out (fp32)
    float* H     = (float*)(ws + off);  off += (size_t)N * 128 * sizeof(float);   // fp32 row-major
    __half* xh   = Ut;  // alias: xh dead after agg1, before gemm2 writes Ut

    const int nb256 = (N + 255) / 256;
    const int ebl = (E + 255) / 256;

    init_kernel<<<nb256, 256, 0, stream>>>(deg, pool, N, NDBL);
    degree_kernel<<<ebl, 256, 0, stream>>>(e_col, deg, E);
    scan1_kernel<<<nb256, 256, 0, stream>>>(deg, dinv, offs, bsums, N);
    scan2_kernel<<<1, 512, 0, stream>>>(bsums, nb256);
    scan3_kernel<<<nb256, 256, 0, stream>>>(offs, bsums, bcur, N);
    binstage_kernel<<<(E + EPB - 1) / EPB, 512, 0, stream>>>(e_row, e_col, bcur, stage, E, nbuckets);
    bucket_sort_kernel<<<nbuckets, 256, 0, stream>>>(stage, offs, csr, N, E);

    // Layer 1: x -> fp16 (dinv-scaled); agg 64-dim -> A1; GEMM(+b1,+stats->tmp1) -> H1
    halfconv_kernel<<<(N * 8 + 255) / 256, 256, 0, stream>>>(x, dinv, xh, N);
    agg_kernel<64, false, false><<<(N + 31) / 32, 256, 0, stream>>>(
        xh, csr, offs, deg, dinv, nullptr, A1, nullptr, N);
    gemm_kernel<64, 128, false, true, false, false, true><<<(N + 63) / 64, 256, 0, stream>>>(
        A1, W1, nullptr, nullptr, b1, dinv, H, tmp1, N);
    finalize_tmp_kernel<128><<<1, 128, 0, stream>>>(tmp1, g1, be1, scale1, shift1, N);

    // Layer 2: GEMM (BN1+GELU fused, dinv prescale, fp16 out) -> Ut; agg(+b2,+stats->tmp2) -> H2
    gemm_kernel<128, 128, true, false, true, true, false><<<(N + 63) / 64, 256, 0, stream>>>(
        H, W2, scale1, shift1, nullptr, dinv, (float*)Ut, nullptr, N);
    agg_kernel<128, true, true><<<(N + 15) / 16, 256, 0, stream>>>(
        Ut, csr, offs, deg, dinv, b2, H, tmp2, N);
    finalize_tmp_kernel<128><<<1, 128, 0, stream>>>(tmp2, g2, be2, scale2, shift2, N);

    // Layer 3: GEMM (BN2+GELU fused, dinv prescale, fp16 out 64) -> Ut; agg(+b3,+stats->tmp3) -> H3
    gemm_kernel<128, 64, true, false, true, true, false><<<(N + 63) / 64, 256, 0, stream>>>(
        H, W3, scale2, shift2, nullptr, dinv, (float*)Ut, nullptr, N);
    agg_kernel<64, true, true><<<(N + 31) / 32, 256, 0, stream>>>(
        Ut, csr, offs, deg, dinv, b3, H, tmp3, N);
    combine_kernel<64><<<1, 128, 0, stream>>>(tmp3, stats3);

    // Epilogue: BN3+GELU+residual+meanpool, then head MLP
    norm_pool_kernel<<<1024, 256, 0, stream>>>(H, x, stats3, g3, be3, pool, N);
    mlp_kernel<<<1, 128, 0, stream>>>(pool, fc1w, fc1b, fc2w, fc2b, fc3w, fc3b,
                                      fc4w, fc4b, (float*)d_out, N);
}

// Round 14
// 398.113 us; speedup vs baseline: 2.3856x; 1.1846x over previous
//
#include <hip/hip_runtime.h>
#include <hip/hip_bf16.h>
#include <hip/hip_fp16.h>
#include <math.h>

// GNN: 3-layer GCN + BN + GELU + residual + meanpool + MLP -> scalar.
// R14: R13 (471us) + MFMA GEMMs. Old fp32 VALU gemm: 85us, VALUBusy 44%,
// occupancy 18% (50KB LDS), 6.4M bank conflicts, MfmaUtil 0. New: per-wave
// 16x16 f16 MFMA tiles (C/D map col=lane&15,row=(lane>>4)*4+reg, HW-verified);
// W pre-swizzled to fragment order (one 16B load per B-frag, L2-resident);
// H staged fp16 in LDS (17KB) with BN+GELU fused; bias/dinv/stats/fp16-out
// in epilogue. fp16 operands already proven (absmax 0.0 since R11).

typedef _Float16 f16x8 __attribute__((ext_vector_type(8)));
typedef _Float16 f16x4 __attribute__((ext_vector_type(4)));
typedef float f32x4 __attribute__((ext_vector_type(4)));

__device__ __forceinline__ float gelu_f(float x) {
    return 0.5f * x * (1.0f + erff(x * 0.7071067811865476f));
}

__device__ __forceinline__ int wave_incl_scan(int v, int lane) {
#pragma unroll
    for (int off = 1; off < 64; off <<= 1) {
        int t = __shfl_up(v, (unsigned)off, 64);
        if (lane >= off) v += t;
    }
    return v;
}

__device__ __forceinline__ void load8h(const __half* __restrict__ p, float* f) {
    uint4 u = *(const uint4*)p;
    const __half2* h2p = (const __half2*)&u;
#pragma unroll
    for (int i = 0; i < 4; i++) {
        float2 t = __half22float2(h2p[i]);
        f[2 * i] = t.x;
        f[2 * i + 1] = t.y;
    }
}

__device__ __forceinline__ void acc8h(const uint4& u, float* f) {
    const __half2* h2p = (const __half2*)&u;
#pragma unroll
    for (int i = 0; i < 4; i++) {
        float2 t = __half22float2(h2p[i]);
        f[2 * i] += t.x;
        f[2 * i + 1] += t.y;
    }
}

// ---- init: deg = 1.0 (self loop), zero double accumulators ----
__global__ void init_kernel(float* __restrict__ deg, double* __restrict__ dbls,
                            int n, int ndbl) {
    int i = blockIdx.x * 256 + threadIdx.x;
    if (i < n) deg[i] = 1.0f;
    if (i < ndbl) dbls[i] = 0.0;
}

__global__ void degree_kernel(const int* __restrict__ col, float* __restrict__ deg, int E) {
    int e = blockIdx.x * 256 + threadIdx.x;
    if (e < E) atomicAdd(&deg[col[e]], 1.0f);
}

__global__ __launch_bounds__(256) void scan1_kernel(const float* __restrict__ deg,
                                                    float* __restrict__ dinv,
                                                    int* __restrict__ offs,
                                                    int* __restrict__ bsums, int n) {
    int i = blockIdx.x * 256 + threadIdx.x;
    int lane = threadIdx.x & 63;
    int wid = threadIdx.x >> 6;
    int cnt = 0;
    if (i < n) {
        float d = deg[i];
        dinv[i] = 1.0f / sqrtf(d);
        cnt = (int)d - 1;
    }
    int incl = wave_incl_scan(cnt, lane);
    __shared__ int ws[4];
    if (lane == 63) ws[wid] = incl;
    __syncthreads();
    if (threadIdx.x == 0) {
        int a = 0;
#pragma unroll
        for (int j = 0; j < 4; j++) { int t = ws[j]; ws[j] = a; a += t; }
        bsums[blockIdx.x] = a;
    }
    __syncthreads();
    int excl = incl - cnt + ws[wid];
    if (i < n) offs[i] = excl;
}

__global__ __launch_bounds__(512) void scan2_kernel(int* __restrict__ bsums, int nblk) {
    int lane = threadIdx.x & 63;
    int wid = threadIdx.x >> 6;
    int v = (threadIdx.x < nblk) ? bsums[threadIdx.x] : 0;
    int incl = wave_incl_scan(v, lane);
    __shared__ int ws[8];
    if (lane == 63) ws[wid] = incl;
    __syncthreads();
    if (threadIdx.x == 0) {
        int a = 0;
#pragma unroll
        for (int j = 0; j < 8; j++) { int t = ws[j]; ws[j] = a; a += t; }
    }
    __syncthreads();
    int excl = incl - v + ws[wid];
    if (threadIdx.x < nblk) bsums[threadIdx.x] = excl;
}

// scan3: finalize offs; init bucket cursors (bucket = 256 nodes)
__global__ void scan3_kernel(int* __restrict__ offs, const int* __restrict__ bsums,
                             int* __restrict__ bcur, int n) {
    int i = blockIdx.x * 256 + threadIdx.x;
    if (i < n) {
        int o = offs[i] + bsums[i >> 8];
        offs[i] = o;
        if ((i & 255) == 0) bcur[i >> 8] = o;
    }
}

// ---- CSR pass 1: LDS-binned stage. One global atomic per (block,bucket). ----
#define EPB 8192
__global__ __launch_bounds__(512) void binstage_kernel(const int* __restrict__ row,
                                                       const int* __restrict__ col,
                                                       int* __restrict__ bcur,
                                                       unsigned int* __restrict__ stage,
                                                       int E, int nbuckets) {
    __shared__ int cnt[512];
    __shared__ int gbase[512];
    int e0 = blockIdx.x * EPB;
    int eend = e0 + EPB;
    if (eend > E) eend = E;
    for (int b = threadIdx.x; b < nbuckets; b += 512) cnt[b] = 0;
    __syncthreads();
    for (int e = e0 + threadIdx.x; e < eend; e += 512)
        atomicAdd(&cnt[col[e] >> 8], 1);
    __syncthreads();
    for (int b = threadIdx.x; b < nbuckets; b += 512) {
        int c = cnt[b];
        gbase[b] = c ? atomicAdd(&bcur[b], c) : 0;
        cnt[b] = 0;  // reuse as local cursor
    }
    __syncthreads();
    for (int e = e0 + threadIdx.x; e < eend; e += 512) {
        int c = col[e];
        int b = c >> 8;
        int lp = atomicAdd(&cnt[b], 1);
        stage[gbase[b] + lp] = ((unsigned int)row[e] << 8) | (unsigned int)(c & 255);
    }
}

// ---- CSR pass 2: one block per bucket, LDS cursors -> exact csr ----
__global__ __launch_bounds__(256) void bucket_sort_kernel(const unsigned int* __restrict__ stage,
                                                          const int* __restrict__ offs,
                                                          int* __restrict__ csr, int N, int E) {
    __shared__ int cur[256];
    int b = blockIdx.x;
    int nb0 = b << 8;
    int base = offs[nb0];
    int nend = nb0 + 256;
    int end = (nend < N) ? offs[nend] : E;
    {
        int node = nb0 + threadIdx.x;
        cur[threadIdx.x] = (node < N) ? (offs[node] - base) : 0;
    }
    __syncthreads();
    int cnt = end - base;
    for (int t = threadIdx.x; t < cnt; t += 256) {
        unsigned int v = stage[base + t];
        int lc = v & 255;
        int src = (int)(v >> 8);
        int pos = atomicAdd(&cur[lc], 1);
        csr[base + pos] = src;
    }
}

// ---- convert x[N][64] fp32 -> xh[N][64] fp16, scaled by dinv[node] ----
__global__ __launch_bounds__(256) void halfconv_kernel(const float* __restrict__ x,
                                                       const float* __restrict__ dinv,
                                                       __half* __restrict__ xh, int N) {
    int t = blockIdx.x * 256 + threadIdx.x;   // one 8-float chunk per thread
    if (t >= N * 8) return;
    int node = t >> 3;
    float dv = dinv[node];
    const float4* p = (const float4*)(x + (size_t)t * 8);
    float4 a = p[0], b = p[1];
    __half2 h[4];
    h[0] = __floats2half2_rn(a.x * dv, a.y * dv);
    h[1] = __floats2half2_rn(a.z * dv, a.w * dv);
    h[2] = __floats2half2_rn(b.x * dv, b.y * dv);
    h[3] = __floats2half2_rn(b.z * dv, b.w * dv);
    *(uint4*)(xh + (size_t)t * 8) = *(uint4*)h;
}

// ---- convert W[DIN][DOUT] fp32 -> fragment-ordered fp16 Wf ----
// B-frag for (kstep s, ntile t): lane l holds W[s*32+(l>>4)*8+j][t*16+(l&15)], j=0..7
template <int DIN, int DOUT>
__global__ void wconv_kernel(const float* __restrict__ W, _Float16* __restrict__ Wf) {
    int i = blockIdx.x * 256 + threadIdx.x;
    if (i >= DIN * DOUT) return;
    int k = i / DOUT, col = i - k * DOUT;
    int s = k >> 5, krem = k & 31;
    int lg = krem >> 3, j = krem & 7;
    int t = col >> 4, c = col & 15;
    constexpr int NT = DOUT / 16;
    int l = lg * 16 + c;
    Wf[((size_t)(s * NT + t) * 64 + l) * 8 + j] = (_Float16)W[(size_t)k * DOUT + col];
}

// ---- aggregation: H[i][D] = dinv_i*(Ut[i] + sum in-edge Ut[src]) (+bias) ----
template <int D, bool STATS, bool BIAS>
__global__ __launch_bounds__(256) void agg_kernel(const __half* __restrict__ Ut,
                                                  const int* __restrict__ csr,
                                                  const int* __restrict__ offs,
                                                  const float* __restrict__ deg,
                                                  const float* __restrict__ dinv,
                                                  const float* __restrict__ bias,
                                                  float* __restrict__ H,
                                                  double* __restrict__ tmp, int n) {
    constexpr int GPN = D / 8;
    constexpr int NPB = 256 / GPN;
    int g = threadIdx.x / GPN;
    int cl = threadIdx.x % GPN;
    int node = blockIdx.x * NPB + g;
    bool act = node < n;

    float a[8], b[8];
#pragma unroll
    for (int c = 0; c < 8; c++) { a[c] = 0.f; b[c] = 0.f; }

    int start = 0, cnt = 0;
    float dvi = 0.f;
    if (act) {
        start = offs[node];
        cnt = (int)deg[node] - 1;
        dvi = dinv[node];
        load8h(Ut + (size_t)node * D + cl * 8, a);   // self loop (pre-scaled)
    }
    const __half* __restrict__ base = Ut + cl * 8;
    int j = 0;
    for (; j + 4 <= cnt; j += 4) {
        int s0 = csr[start + j];
        int s1 = csr[start + j + 1];
        int s2 = csr[start + j + 2];
        int s3 = csr[start + j + 3];
        uint4 u0 = *(const uint4*)(base + (size_t)s0 * D);
        uint4 u1 = *(const uint4*)(base + (size_t)s1 * D);
        uint4 u2 = *(const uint4*)(base + (size_t)s2 * D);
        uint4 u3 = *(const uint4*)(base + (size_t)s3 * D);
        acc8h(u0, a);
        acc8h(u1, b);
        acc8h(u2, a);
        acc8h(u3, b);
    }
    if (j + 2 <= cnt) {
        int s0 = csr[start + j];
        int s1 = csr[start + j + 1];
        uint4 u0 = *(const uint4*)(base + (size_t)s0 * D);
        uint4 u1 = *(const uint4*)(base + (size_t)s1 * D);
        acc8h(u0, a);
        acc8h(u1, b);
        j += 2;
    }
    if (j < cnt) {
        int s0 = csr[start + j];
        uint4 u0 = *(const uint4*)(base + (size_t)s0 * D);
        acc8h(u0, a);
    }

    float h[8];
#pragma unroll
    for (int c = 0; c < 8; c++) h[c] = (a[c] + b[c]) * dvi;
    if (BIAS) {
#pragma unroll
        for (int c = 0; c < 8; c++) h[c] += bias[cl * 8 + c];
    }
    if (act) {
        float* dst = H + (size_t)node * D + cl * 8;
        *(float4*)dst = make_float4(h[0], h[1], h[2], h[3]);
        *(float4*)(dst + 4) = make_float4(h[4], h[5], h[6], h[7]);
    } else {
#pragma unroll
        for (int c = 0; c < 8; c++) h[c] = 0.f;   // no stats contribution
    }

    if constexpr (STATS) {
        float s[8], q[8];
#pragma unroll
        for (int c = 0; c < 8; c++) { s[c] = h[c]; q[c] = h[c] * h[c]; }
#pragma unroll
        for (int m = GPN; m < 64; m <<= 1) {
#pragma unroll
            for (int c = 0; c < 8; c++) {
                s[c] += __shfl_xor(s[c], m, 64);
                q[c] += __shfl_xor(q[c], m, 64);
            }
        }
        __shared__ float ps[4][GPN][8], pq[4][GPN][8];
        int wid = threadIdx.x >> 6;
        int lane = threadIdx.x & 63;
        if (lane < GPN) {
#pragma unroll
            for (int c = 0; c < 8; c++) { ps[wid][lane][c] = s[c]; pq[wid][lane][c] = q[c]; }
        }
        __syncthreads();
        if (threadIdx.x < D) {
            int cgi = threadIdx.x >> 3, ci = threadIdx.x & 7;
            float t1 = ps[0][cgi][ci] + ps[1][cgi][ci] + ps[2][cgi][ci] + ps[3][cgi][ci];
            float t2 = pq[0][cgi][ci] + pq[1][cgi][ci] + pq[2][cgi][ci] + pq[3][cgi][ci];
            int cp = (blockIdx.x & 63) * 2 * D;
            atomicAdd(&tmp[cp + threadIdx.x], (double)t1);
            atomicAdd(&tmp[cp + D + threadIdx.x], (double)t2);
        }
    }
}

// ---- MFMA GEMM: Out[n][DOUT] = f(Hin)[n][DIN] @ W (+bias)(*dinv) ----
// Block = 256 thr = 4 waves; wave w computes rows [blk*64 + w*16, +16) x DOUT.
// A-frag: lane l row=(l&15), k=(l>>4)*8+j from LDS fp16; B-frag: one 16B load
// from pre-swizzled Wf. Acc: mfma_f32_16x16x32_f16, C/D col=l&15,row=(l>>4)*4+r.
template <int DIN, int DOUT, bool BNIN, bool BIAS, bool DINVOUT, bool HALFOUT, bool STATS>
__global__ __launch_bounds__(256) void mgemm_kernel(const float* __restrict__ Hin,
                                                    const _Float16* __restrict__ Wf,
                                                    const float* __restrict__ scale,
                                                    const float* __restrict__ shift,
                                                    const float* __restrict__ bias,
                                                    const float* __restrict__ dinv,
                                                    void* __restrict__ Out,
                                                    double* __restrict__ tmp, int n) {
    constexpr int NT = DOUT / 16;   // n-tiles per wave
    constexpr int NS = DIN / 32;    // k-steps
    constexpr int DP = DIN + 8;     // padded LDS row (halfs), keeps 16B align
    __shared__ _Float16 Hs[64 * DP];

    int node0 = blockIdx.x * 64;
    int nv = n - node0;
    if (nv > 64) nv = 64;

    // stage H tile -> fp16 LDS (BN+GELU fused), zero-pad invalid rows
    constexpr int C4R = DIN / 4;
    for (int f = threadIdx.x; f < 64 * C4R; f += 256) {
        int nn = f / C4R, k4 = f - nn * C4R;
        float4 v = make_float4(0.f, 0.f, 0.f, 0.f);
        if (nn < nv)
            v = *(const float4*)(Hin + (size_t)(node0 + nn) * DIN + k4 * 4);
        if (BNIN) {
            float4 sc = *(const float4*)(scale + k4 * 4);
            float4 sh = *(const float4*)(shift + k4 * 4);
            v.x = gelu_f(fmaf(v.x, sc.x, sh.x));
            v.y = gelu_f(fmaf(v.y, sc.y, sh.y));
            v.z = gelu_f(fmaf(v.z, sc.z, sh.z));
            v.w = gelu_f(fmaf(v.w, sc.w, sh.w));
        }
        f16x4 h;
        h[0] = (_Float16)v.x; h[1] = (_Float16)v.y;
        h[2] = (_Float16)v.z; h[3] = (_Float16)v.w;
        *(f16x4*)(&Hs[nn * DP + k4 * 4]) = h;
    }
    __syncthreads();

    int wv = threadIdx.x >> 6;
    int l = threadIdx.x & 63;
    int arow = l & 15, agrp = l >> 4;

    f32x4 acc[NT];
#pragma unroll
    for (int t = 0; t < NT; t++) acc[t] = (f32x4){0.f, 0.f, 0.f, 0.f};

    const _Float16* hrow = &Hs[(wv * 16 + arow) * DP];
#pragma unroll
    for (int s = 0; s < NS; s++) {
        f16x8 a = *(const f16x8*)(hrow + s * 32 + agrp * 8);
        const _Float16* wb = Wf + (size_t)s * NT * 512 + l * 8;
#pragma unroll
        for (int t = 0; t < NT; t++) {
            f16x8 b = *(const f16x8*)(wb + (size_t)t * 512);
            acc[t] = __builtin_amdgcn_mfma_f32_16x16x32_f16(a, b, acc[t], 0, 0, 0);
        }
    }

    // epilogue: lane covers rows rbase..rbase+3, col t*16+arow
    int rbase = wv * 16 + agrp * 4;
    float dv4[4] = {1.f, 1.f, 1.f, 1.f};
    if (DINVOUT) {
#pragma unroll
        for (int r = 0; r < 4; r++)
            if (rbase + r < nv) dv4[r] = dinv[node0 + rbase + r];
    }
    float sa[NT], qa[NT];
#pragma unroll
    for (int t = 0; t < NT; t++) {
        int col = t * 16 + arow;
        float bcol = BIAS ? bias[col] : 0.f;
        float ssum = 0.f, qsum = 0.f;
#pragma unroll
        for (int r = 0; r < 4; r++) {
            int nn = rbase + r;
            bool valid = nn < nv;
            float v = acc[t][r];
            if (DINVOUT) v *= dv4[r];
            v += bcol;
            v = valid ? v : 0.f;
            if (valid) {
                size_t oi = (size_t)(node0 + nn) * DOUT + col;
                if (HALFOUT) ((__half*)Out)[oi] = __float2half(v);
                else ((float*)Out)[oi] = v;
            }
            ssum += v;
            qsum += v * v;
        }
        sa[t] = ssum;
        qa[t] = qsum;
    }

    if constexpr (STATS) {
        __shared__ float ps[4][DOUT], pq[4][DOUT];
#pragma unroll
        for (int t = 0; t < NT; t++) {
            float s = sa[t], q = qa[t];
            s += __shfl_xor(s, 16, 64); q += __shfl_xor(q, 16, 64);
            s += __shfl_xor(s, 32, 64); q += __shfl_xor(q, 32, 64);
            if (l < 16) { ps[wv][t * 16 + l] = s; pq[wv][t * 16 + l] = q; }
        }
        __syncthreads();
        if (threadIdx.x < DOUT) {
            float t1 = ps[0][threadIdx.x] + ps[1][threadIdx.x] +
                       ps[2][threadIdx.x] + ps[3][threadIdx.x];
            float t2 = pq[0][threadIdx.x] + pq[1][threadIdx.x] +
                       pq[2][threadIdx.x] + pq[3][threadIdx.x];
            int cp = (blockIdx.x & 63) * 2 * DOUT;
            atomicAdd(&tmp[cp + threadIdx.x], (double)t1);
            atomicAdd(&tmp[cp + DOUT + threadIdx.x], (double)t2);
        }
    }
}

// ---- fold 64 tmp copies -> per-channel scale/shift floats ----
template <int D>
__global__ void finalize_tmp_kernel(const double* __restrict__ tmp,
                                    const float* __restrict__ g, const float* __restrict__ be,
                                    float* __restrict__ scale, float* __restrict__ shift, int n) {
    int c = threadIdx.x;
    if (c < D) {
        double s = 0.0, q = 0.0;
        for (int gg = 0; gg < 64; gg++) {
            s += tmp[gg * 2 * D + c];
            q += tmp[gg * 2 * D + D + c];
        }
        double mu = s / n;
        double var = q / n - mu * mu;
        double inv = 1.0 / sqrt(var + 1e-5);
        double sc = (double)g[c] * inv;
        scale[c] = (float)sc;
        shift[c] = (float)((double)be[c] - mu * sc);
    }
}

// ---- fold 64 tmp copies -> raw stats sums (for norm_pool) ----
template <int D>
__global__ void combine_kernel(const double* __restrict__ tmp, double* __restrict__ stats) {
    int t = threadIdx.x;
    if (t < 2 * D) {
        double s = 0.0;
        for (int gg = 0; gg < 64; gg++) s += tmp[gg * 2 * D + t];
        stats[t] = s;
    }
}

// ---- layer-3: BN normalize + GELU + residual(x) + mean-pool accumulate ----
__global__ __launch_bounds__(256) void norm_pool_kernel(const float* __restrict__ X3,
                                                        const float* __restrict__ x0,
                                                        const double* __restrict__ stats,
                                                        const float* __restrict__ gw,
                                                        const float* __restrict__ be,
                                                        double* __restrict__ pool, int n) {
    constexpr int D = 64;
    constexpr int RPB = 4;
    int c = threadIdx.x % D;
    double mu = stats[c] / n;
    double var = stats[c + D] / n - mu * mu;
    double inv = 1.0 / sqrt(var + 1e-5);
    float scale = (float)((double)gw[c] * inv);
    float shift = (float)((double)be[c] - mu * (double)gw[c] * inv);
    int r0 = threadIdx.x / D;
    int rowsPerGrid = gridDim.x * RPB;
    double s = 0.0;
    for (int r = blockIdx.x * RPB + r0; r < n; r += rowsPerGrid) {
        size_t idx = (size_t)r * D + c;
        float t = fmaf(X3[idx], scale, shift);
        float res = x0[idx] + gelu_f(t);
        s += res;
    }
    __shared__ double sh[256];
    sh[threadIdx.x] = s;
    __syncthreads();
    if (threadIdx.x < D) {
#pragma unroll
        for (int j = 1; j < RPB; j++) s += sh[threadIdx.x + j * D];
        atomicAdd(&pool[c], s);
    }
}

// ---- head MLP: 64 ->128 ->64 ->32 ->1, single block ----
__global__ __launch_bounds__(128) void mlp_kernel(const double* __restrict__ pool,
                                                  const float* __restrict__ w1, const float* __restrict__ b1,
                                                  const float* __restrict__ w2, const float* __restrict__ b2,
                                                  const float* __restrict__ w3, const float* __restrict__ b3,
                                                  const float* __restrict__ w4, const float* __restrict__ b4,
                                                  float* __restrict__ out, int n) {
    __shared__ float v0[64], h1[128], h2[64], h3[32];
    int t = threadIdx.x;
    if (t < 64) v0[t] = (float)(pool[t] / (double)n);
    __syncthreads();
    if (t < 128) {
        float a = b1[t];
        for (int k = 0; k < 64; k++) a = fmaf(v0[k], w1[k * 128 + t], a);
        h1[t] = gelu_f(a);
    }
    __syncthreads();
    if (t < 64) {
        float a = b2[t];
        for (int k = 0; k < 128; k++) a = fmaf(h1[k], w2[k * 64 + t], a);
        h2[t] = gelu_f(a);
    }
    __syncthreads();
    if (t < 32) {
        float a = b3[t];
        for (int k = 0; k < 64; k++) a = fmaf(h2[k], w3[k * 32 + t], a);
        h3[t] = gelu_f(a);
    }
    __syncthreads();
    if (t == 0) {
        float a = b4[0];
        for (int k = 0; k < 32; k++) a = fmaf(h3[k], w4[k], a);
        out[0] = a;
    }
}

extern "C" void kernel_launch(void* const* d_in, const int* in_sizes, int n_in,
                              void* d_out, int out_size, void* d_ws, size_t ws_size,
                              hipStream_t stream) {
    const float* x    = (const float*)d_in[0];
    const int*   ei   = (const int*)d_in[1];
    const float* W1   = (const float*)d_in[2];
    const float* b1   = (const float*)d_in[3];
    const float* g1   = (const float*)d_in[4];
    const float* be1  = (const float*)d_in[5];
    const float* W2   = (const float*)d_in[6];
    const float* b2   = (const float*)d_in[7];
    const float* g2   = (const float*)d_in[8];
    const float* be2  = (const float*)d_in[9];
    const float* W3   = (const float*)d_in[10];
    const float* b3   = (const float*)d_in[11];
    const float* g3   = (const float*)d_in[12];
    const float* be3  = (const float*)d_in[13];
    const float* fc1w = (const float*)d_in[14];
    const float* fc1b = (const float*)d_in[15];
    const float* fc2w = (const float*)d_in[16];
    const float* fc2b = (const float*)d_in[17];
    const float* fc3w = (const float*)d_in[18];
    const float* fc3b = (const float*)d_in[19];
    const float* fc4w = (const float*)d_in[20];
    const float* fc4b = (const float*)d_in[21];

    const int N = in_sizes[0] / 64;
    const int E = in_sizes[1] / 2;
    const int* e_row = ei;       // source
    const int* e_col = ei + E;   // target (aggregation index)
    const int nbuckets = (N + 255) >> 8;

    // ---- workspace layout (~112 MB) ----
    char* ws = (char*)d_ws;
    size_t off = 0;
    double* pool   = (double*)(ws + off); off += 64 * sizeof(double);
    double* tmp1   = (double*)(ws + off); off += 64 * 256 * sizeof(double);  // gemm1 stats spread
    double* tmp2   = (double*)(ws + off); off += 64 * 256 * sizeof(double);  // agg2 stats spread
    double* tmp3   = (double*)(ws + off); off += 64 * 128 * sizeof(double);  // agg3 stats spread
    double* stats3 = (double*)(ws + off); off += 128 * sizeof(double);
    const int NDBL = 64 + 64 * 256 * 2 + 64 * 128 + 128;  // zeroed by init
    float* scale1 = (float*)(ws + off); off += 128 * sizeof(float);
    float* shift1 = (float*)(ws + off); off += 128 * sizeof(float);
    float* scale2 = (float*)(ws + off); off += 128 * sizeof(float);
    float* shift2 = (float*)(ws + off); off += 128 * sizeof(float);
    _Float16* Wf1 = (_Float16*)(ws + off); off += 64 * 128 * sizeof(_Float16);
    _Float16* Wf2 = (_Float16*)(ws + off); off += 128 * 128 * sizeof(_Float16);
    _Float16* Wf3 = (_Float16*)(ws + off); off += 128 * 64 * sizeof(_Float16);
    float* deg   = (float*)(ws + off); off += (size_t)N * sizeof(float);
    float* dinv  = (float*)(ws + off); off += (size_t)N * sizeof(float);
    off = (off + 15) & ~(size_t)15;
    int* offs    = (int*)(ws + off); off += (size_t)N * sizeof(int);
    int* bcur    = (int*)(ws + off); off += 512 * sizeof(int);
    int* bsums   = (int*)(ws + off); off += 512 * sizeof(int);
    int* csr     = (int*)(ws + off); off += (size_t)E * sizeof(int);
    unsigned int* stage = (unsigned int*)(ws + off); off += (size_t)E * sizeof(unsigned int);
    off = (off + 255) & ~(size_t)255;
    __half* Ut   = (__half*)(ws + off); off += (size_t)N * 128 * sizeof(__half);  // fp16 gather table
    float* A1    = (float*)(ws + off);  off += (size_t)N * 64 * sizeof(float);    // agg1 out (fp32)
    float* H     = (float*)(ws + off);  off += (size_t)N * 128 * sizeof(float);   // fp32 row-major
    __half* xh   = Ut;  // alias: xh dead after agg1, before gemm2 writes Ut

    const int nb256 = (N + 255) / 256;
    const int ebl = (E + 255) / 256;
    const int gblk = (N + 63) / 64;

    init_kernel<<<nb256, 256, 0, stream>>>(deg, pool, N, NDBL);
    degree_kernel<<<ebl, 256, 0, stream>>>(e_col, deg, E);
    scan1_kernel<<<nb256, 256, 0, stream>>>(deg, dinv, offs, bsums, N);
    scan2_kernel<<<1, 512, 0, stream>>>(bsums, nb256);
    scan3_kernel<<<nb256, 256, 0, stream>>>(offs, bsums, bcur, N);
    binstage_kernel<<<(E + EPB - 1) / EPB, 512, 0, stream>>>(e_row, e_col, bcur, stage, E, nbuckets);
    bucket_sort_kernel<<<nbuckets, 256, 0, stream>>>(stage, offs, csr, N, E);

    // W -> fragment-ordered fp16 (tiny, once)
    wconv_kernel<64, 128><<<32, 256, 0, stream>>>(W1, Wf1);
    wconv_kernel<128, 128><<<64, 256, 0, stream>>>(W2, Wf2);
    wconv_kernel<128, 64><<<32, 256, 0, stream>>>(W3, Wf3);

    // Layer 1: x -> fp16 (dinv-scaled); agg 64-dim -> A1; MFMA GEMM(+b1,+stats) -> H1
    halfconv_kernel<<<(N * 8 + 255) / 256, 256, 0, stream>>>(x, dinv, xh, N);
    agg_kernel<64, false, false><<<(N + 31) / 32, 256, 0, stream>>>(
        xh, csr, offs, deg, dinv, nullptr, A1, nullptr, N);
    mgemm_kernel<64, 128, false, true, false, false, true><<<gblk, 256, 0, stream>>>(
        A1, Wf1, nullptr, nullptr, b1, nullptr, H, tmp1, N);
    finalize_tmp_kernel<128><<<1, 128, 0, stream>>>(tmp1, g1, be1, scale1, shift1, N);

    // Layer 2: MFMA GEMM (BN1+GELU fused, dinv prescale, fp16 out) -> Ut; agg -> H2
    mgemm_kernel<128, 128, true, false, true, true, false><<<gblk, 256, 0, stream>>>(
        H, Wf2, scale1, shift1, nullptr, dinv, Ut, nullptr, N);
    agg_kernel<128, true, true><<<(N + 15) / 16, 256, 0, stream>>>(
        Ut, csr, offs, deg, dinv, b2, H, tmp2, N);
    finalize_tmp_kernel<128><<<1, 128, 0, stream>>>(tmp2, g2, be2, scale2, shift2, N);

    // Layer 3: MFMA GEMM (BN2+GELU fused, dinv prescale, fp16 out 64) -> Ut; agg -> H3
    mgemm_kernel<128, 64, true, false, true, true, false><<<gblk, 256, 0, stream>>>(
        H, Wf3, scale2, shift2, nullptr, dinv, Ut, nullptr, N);
    agg_kernel<64, true, true><<<(N + 31) / 32, 256, 0, stream>>>(
        Ut, csr, offs, deg, dinv, b3, H, tmp3, N);
    combine_kernel<64><<<1, 128, 0, stream>>>(tmp3, stats3);

    // Epilogue: BN3+GELU+residual+meanpool, then head MLP
    norm_pool_kernel<<<1024, 256, 0, stream>>>(H, x, stats3, g3, be3, pool, N);
    mlp_kernel<<<1, 128, 0, stream>>>(pool, fc1w, fc1b, fc2w, fc2b, fc3w, fc3b,
                                      fc4w, fc4b, (float*)d_out, N);
}

// Round 15
// 319.065 us; speedup vs baseline: 2.9767x; 1.2478x over previous
//
#include <hip/hip_runtime.h>
#include <hip/hip_bf16.h>
#include <hip/hip_fp16.h>
#include <math.h>

// GNN: 3-layer GCN + BN + GELU + residual + meanpool + MLP -> scalar.
// R15: R14 (398us) + degree counting folded into the bucket pipeline.
// degree_kernel was 83us (50MB WRITE: 1.6M random 4B atomic-RMWs, the same
// write-amp pathology as fill). New CSR build: coarse_count (LDS histogram,
// 1 atomic/(block,bucket) onto 391 counters) -> bucket_scan (1 block) ->
// binstage (unchanged) -> bucket_finalize (per-bucket local degrees in LDS,
// in-block scan, COALESCED deg/dinv/offs writes + csr placement).
// degree/scan1/scan2/scan3/bucket_sort all deleted. agg/MFMA-gemm = R14.

typedef _Float16 f16x8 __attribute__((ext_vector_type(8)));
typedef _Float16 f16x4 __attribute__((ext_vector_type(4)));
typedef float f32x4 __attribute__((ext_vector_type(4)));

__device__ __forceinline__ float gelu_f(float x) {
    return 0.5f * x * (1.0f + erff(x * 0.7071067811865476f));
}

__device__ __forceinline__ int wave_incl_scan(int v, int lane) {
#pragma unroll
    for (int off = 1; off < 64; off <<= 1) {
        int t = __shfl_up(v, (unsigned)off, 64);
        if (lane >= off) v += t;
    }
    return v;
}

__device__ __forceinline__ void load8h(const __half* __restrict__ p, float* f) {
    uint4 u = *(const uint4*)p;
    const __half2* h2p = (const __half2*)&u;
#pragma unroll
    for (int i = 0; i < 4; i++) {
        float2 t = __half22float2(h2p[i]);
        f[2 * i] = t.x;
        f[2 * i + 1] = t.y;
    }
}

__device__ __forceinline__ void acc8h(const uint4& u, float* f) {
    const __half2* h2p = (const __half2*)&u;
#pragma unroll
    for (int i = 0; i < 4; i++) {
        float2 t = __half22float2(h2p[i]);
        f[2 * i] += t.x;
        f[2 * i + 1] += t.y;
    }
}

// ---- init: zero double accumulators + bucket counters ----
__global__ void init_kernel(double* __restrict__ dbls, int ndbl, int* __restrict__ bucketCnt) {
    int i = blockIdx.x * 256 + threadIdx.x;
    if (i < ndbl) dbls[i] = 0.0;
    if (i < 512) bucketCnt[i] = 0;
}

// ---- CSR step 1: coarse per-bucket edge counts (LDS histogram) ----
#define EPB 8192
__global__ __launch_bounds__(512) void coarse_count_kernel(const int* __restrict__ col,
                                                           int* __restrict__ bucketCnt,
                                                           int E, int nbuckets) {
    __shared__ int cnt[512];
    for (int b = threadIdx.x; b < nbuckets; b += 512) cnt[b] = 0;
    __syncthreads();
    int e0 = blockIdx.x * EPB;
    int eend = e0 + EPB;
    if (eend > E) eend = E;
    for (int e = e0 + threadIdx.x; e < eend; e += 512)
        atomicAdd(&cnt[col[e] >> 8], 1);
    __syncthreads();
    for (int b = threadIdx.x; b < nbuckets; b += 512) {
        int c = cnt[b];
        if (c) atomicAdd(&bucketCnt[b], c);
    }
}

// ---- CSR step 2: exclusive scan of bucket counts -> bases; init bcur ----
__global__ __launch_bounds__(512) void bucket_scan_kernel(const int* __restrict__ bucketCnt,
                                                          int* __restrict__ bucketBase,
                                                          int* __restrict__ bcur,
                                                          int nbuckets, int E) {
    int lane = threadIdx.x & 63;
    int wid = threadIdx.x >> 6;
    int v = (threadIdx.x < nbuckets) ? bucketCnt[threadIdx.x] : 0;
    int incl = wave_incl_scan(v, lane);
    __shared__ int ws[8];
    if (lane == 63) ws[wid] = incl;
    __syncthreads();
    if (threadIdx.x == 0) {
        int a = 0;
#pragma unroll
        for (int j = 0; j < 8; j++) { int t = ws[j]; ws[j] = a; a += t; }
    }
    __syncthreads();
    int excl = incl - v + ws[wid];
    if (threadIdx.x < nbuckets) {
        bucketBase[threadIdx.x] = excl;
        bcur[threadIdx.x] = excl;
    }
    if (threadIdx.x == 0) bucketBase[nbuckets] = E;
}

// ---- CSR step 3: LDS-binned stage. One global atomic per (block,bucket). ----
__global__ __launch_bounds__(512) void binstage_kernel(const int* __restrict__ row,
                                                       const int* __restrict__ col,
                                                       int* __restrict__ bcur,
                                                       unsigned int* __restrict__ stage,
                                                       int E, int nbuckets) {
    __shared__ int cnt[512];
    __shared__ int gbase[512];
    int e0 = blockIdx.x * EPB;
    int eend = e0 + EPB;
    if (eend > E) eend = E;
    for (int b = threadIdx.x; b < nbuckets; b += 512) cnt[b] = 0;
    __syncthreads();
    for (int e = e0 + threadIdx.x; e < eend; e += 512)
        atomicAdd(&cnt[col[e] >> 8], 1);
    __syncthreads();
    for (int b = threadIdx.x; b < nbuckets; b += 512) {
        int c = cnt[b];
        gbase[b] = c ? atomicAdd(&bcur[b], c) : 0;
        cnt[b] = 0;  // reuse as local cursor
    }
    __syncthreads();
    for (int e = e0 + threadIdx.x; e < eend; e += 512) {
        int c = col[e];
        int b = c >> 8;
        int lp = atomicAdd(&cnt[b], 1);
        stage[gbase[b] + lp] = ((unsigned int)row[e] << 8) | (unsigned int)(c & 255);
    }
}

// ---- CSR step 4: per-bucket degrees (coalesced deg/dinv/offs) + csr fill ----
__global__ __launch_bounds__(256) void bucket_finalize_kernel(const unsigned int* __restrict__ stage,
                                                              const int* __restrict__ bucketBase,
                                                              float* __restrict__ deg,
                                                              float* __restrict__ dinv,
                                                              int* __restrict__ offs,
                                                              int* __restrict__ csr,
                                                              int N) {
    __shared__ int cnt[256];
    __shared__ int loc[256];
    __shared__ int ws[4];
    int b = blockIdx.x;
    int nb0 = b << 8;
    int base = bucketBase[b];
    int end = bucketBase[b + 1];
    cnt[threadIdx.x] = 0;
    __syncthreads();
    int m = end - base;
    for (int t = threadIdx.x; t < m; t += 256)
        atomicAdd(&cnt[stage[base + t] & 255], 1);
    __syncthreads();
    int c = cnt[threadIdx.x];
    int lane = threadIdx.x & 63;
    int wid = threadIdx.x >> 6;
    int incl = wave_incl_scan(c, lane);
    if (lane == 63) ws[wid] = incl;
    __syncthreads();
    if (threadIdx.x == 0) {
        int a = 0;
#pragma unroll
        for (int j = 0; j < 4; j++) { int t = ws[j]; ws[j] = a; a += t; }
    }
    __syncthreads();
    int excl = incl - c + ws[wid];
    int node = nb0 + threadIdx.x;
    if (node < N) {
        float d = (float)(c + 1);
        deg[node] = d;
        dinv[node] = 1.0f / sqrtf(d);
        offs[node] = base + excl;
    }
    loc[threadIdx.x] = excl;
    __syncthreads();
    for (int t = threadIdx.x; t < m; t += 256) {
        unsigned int v = stage[base + t];
        int lc = v & 255;
        int src = (int)(v >> 8);
        int pos = atomicAdd(&loc[lc], 1);
        csr[base + pos] = src;
    }
}

// ---- convert x[N][64] fp32 -> xh[N][64] fp16, scaled by dinv[node] ----
__global__ __launch_bounds__(256) void halfconv_kernel(const float* __restrict__ x,
                                                       const float* __restrict__ dinv,
                                                       __half* __restrict__ xh, int N) {
    int t = blockIdx.x * 256 + threadIdx.x;   // one 8-float chunk per thread
    if (t >= N * 8) return;
    int node = t >> 3;
    float dv = dinv[node];
    const float4* p = (const float4*)(x + (size_t)t * 8);
    float4 a = p[0], b = p[1];
    __half2 h[4];
    h[0] = __floats2half2_rn(a.x * dv, a.y * dv);
    h[1] = __floats2half2_rn(a.z * dv, a.w * dv);
    h[2] = __floats2half2_rn(b.x * dv, b.y * dv);
    h[3] = __floats2half2_rn(b.z * dv, b.w * dv);
    *(uint4*)(xh + (size_t)t * 8) = *(uint4*)h;
}

// ---- convert W[DIN][DOUT] fp32 -> fragment-ordered fp16 Wf ----
template <int DIN, int DOUT>
__global__ void wconv_kernel(const float* __restrict__ W, _Float16* __restrict__ Wf) {
    int i = blockIdx.x * 256 + threadIdx.x;
    if (i >= DIN * DOUT) return;
    int k = i / DOUT, col = i - k * DOUT;
    int s = k >> 5, krem = k & 31;
    int lg = krem >> 3, j = krem & 7;
    int t = col >> 4, c = col & 15;
    constexpr int NT = DOUT / 16;
    int l = lg * 16 + c;
    Wf[((size_t)(s * NT + t) * 64 + l) * 8 + j] = (_Float16)W[(size_t)k * DOUT + col];
}

// ---- aggregation: H[i][D] = dinv_i*(Ut[i] + sum in-edge Ut[src]) (+bias) ----
template <int D, bool STATS, bool BIAS>
__global__ __launch_bounds__(256) void agg_kernel(const __half* __restrict__ Ut,
                                                  const int* __restrict__ csr,
                                                  const int* __restrict__ offs,
                                                  const float* __restrict__ deg,
                                                  const float* __restrict__ dinv,
                                                  const float* __restrict__ bias,
                                                  float* __restrict__ H,
                                                  double* __restrict__ tmp, int n) {
    constexpr int GPN = D / 8;
    constexpr int NPB = 256 / GPN;
    int g = threadIdx.x / GPN;
    int cl = threadIdx.x % GPN;
    int node = blockIdx.x * NPB + g;
    bool act = node < n;

    float a[8], b[8];
#pragma unroll
    for (int c = 0; c < 8; c++) { a[c] = 0.f; b[c] = 0.f; }

    int start = 0, cnt = 0;
    float dvi = 0.f;
    if (act) {
        start = offs[node];
        cnt = (int)deg[node] - 1;
        dvi = dinv[node];
        load8h(Ut + (size_t)node * D + cl * 8, a);   // self loop (pre-scaled)
    }
    const __half* __restrict__ base = Ut + cl * 8;
    int j = 0;
    for (; j + 4 <= cnt; j += 4) {
        int s0 = csr[start + j];
        int s1 = csr[start + j + 1];
        int s2 = csr[start + j + 2];
        int s3 = csr[start + j + 3];
        uint4 u0 = *(const uint4*)(base + (size_t)s0 * D);
        uint4 u1 = *(const uint4*)(base + (size_t)s1 * D);
        uint4 u2 = *(const uint4*)(base + (size_t)s2 * D);
        uint4 u3 = *(const uint4*)(base + (size_t)s3 * D);
        acc8h(u0, a);
        acc8h(u1, b);
        acc8h(u2, a);
        acc8h(u3, b);
    }
    if (j + 2 <= cnt) {
        int s0 = csr[start + j];
        int s1 = csr[start + j + 1];
        uint4 u0 = *(const uint4*)(base + (size_t)s0 * D);
        uint4 u1 = *(const uint4*)(base + (size_t)s1 * D);
        acc8h(u0, a);
        acc8h(u1, b);
        j += 2;
    }
    if (j < cnt) {
        int s0 = csr[start + j];
        uint4 u0 = *(const uint4*)(base + (size_t)s0 * D);
        acc8h(u0, a);
    }

    float h[8];
#pragma unroll
    for (int c = 0; c < 8; c++) h[c] = (a[c] + b[c]) * dvi;
    if (BIAS) {
#pragma unroll
        for (int c = 0; c < 8; c++) h[c] += bias[cl * 8 + c];
    }
    if (act) {
        float* dst = H + (size_t)node * D + cl * 8;
        *(float4*)dst = make_float4(h[0], h[1], h[2], h[3]);
        *(float4*)(dst + 4) = make_float4(h[4], h[5], h[6], h[7]);
    } else {
#pragma unroll
        for (int c = 0; c < 8; c++) h[c] = 0.f;   // no stats contribution
    }

    if constexpr (STATS) {
        float s[8], q[8];
#pragma unroll
        for (int c = 0; c < 8; c++) { s[c] = h[c]; q[c] = h[c] * h[c]; }
#pragma unroll
        for (int m = GPN; m < 64; m <<= 1) {
#pragma unroll
            for (int c = 0; c < 8; c++) {
                s[c] += __shfl_xor(s[c], m, 64);
                q[c] += __shfl_xor(q[c], m, 64);
            }
        }
        __shared__ float ps[4][GPN][8], pq[4][GPN][8];
        int wid = threadIdx.x >> 6;
        int lane = threadIdx.x & 63;
        if (lane < GPN) {
#pragma unroll
            for (int c = 0; c < 8; c++) { ps[wid][lane][c] = s[c]; pq[wid][lane][c] = q[c]; }
        }
        __syncthreads();
        if (threadIdx.x < D) {
            int cgi = threadIdx.x >> 3, ci = threadIdx.x & 7;
            float t1 = ps[0][cgi][ci] + ps[1][cgi][ci] + ps[2][cgi][ci] + ps[3][cgi][ci];
            float t2 = pq[0][cgi][ci] + pq[1][cgi][ci] + pq[2][cgi][ci] + pq[3][cgi][ci];
            int cp = (blockIdx.x & 63) * 2 * D;
            atomicAdd(&tmp[cp + threadIdx.x], (double)t1);
            atomicAdd(&tmp[cp + D + threadIdx.x], (double)t2);
        }
    }
}

// ---- MFMA GEMM: Out[n][DOUT] = f(Hin)[n][DIN] @ W (+bias)(*dinv) ----
template <int DIN, int DOUT, bool BNIN, bool BIAS, bool DINVOUT, bool HALFOUT, bool STATS>
__global__ __launch_bounds__(256) void mgemm_kernel(const float* __restrict__ Hin,
                                                    const _Float16* __restrict__ Wf,
                                                    const float* __restrict__ scale,
                                                    const float* __restrict__ shift,
                                                    const float* __restrict__ bias,
                                                    const float* __restrict__ dinv,
                                                    void* __restrict__ Out,
                                                    double* __restrict__ tmp, int n) {
    constexpr int NT = DOUT / 16;   // n-tiles per wave
    constexpr int NS = DIN / 32;    // k-steps
    constexpr int DP = DIN + 8;     // padded LDS row (halfs), keeps 16B align
    __shared__ _Float16 Hs[64 * DP];

    int node0 = blockIdx.x * 64;
    int nv = n - node0;
    if (nv > 64) nv = 64;

    constexpr int C4R = DIN / 4;
    for (int f = threadIdx.x; f < 64 * C4R; f += 256) {
        int nn = f / C4R, k4 = f - nn * C4R;
        float4 v = make_float4(0.f, 0.f, 0.f, 0.f);
        if (nn < nv)
            v = *(const float4*)(Hin + (size_t)(node0 + nn) * DIN + k4 * 4);
        if (BNIN) {
            float4 sc = *(const float4*)(scale + k4 * 4);
            float4 sh = *(const float4*)(shift + k4 * 4);
            v.x = gelu_f(fmaf(v.x, sc.x, sh.x));
            v.y = gelu_f(fmaf(v.y, sc.y, sh.y));
            v.z = gelu_f(fmaf(v.z, sc.z, sh.z));
            v.w = gelu_f(fmaf(v.w, sc.w, sh.w));
        }
        f16x4 h;
        h[0] = (_Float16)v.x; h[1] = (_Float16)v.y;
        h[2] = (_Float16)v.z; h[3] = (_Float16)v.w;
        *(f16x4*)(&Hs[nn * DP + k4 * 4]) = h;
    }
    __syncthreads();

    int wv = threadIdx.x >> 6;
    int l = threadIdx.x & 63;
    int arow = l & 15, agrp = l >> 4;

    f32x4 acc[NT];
#pragma unroll
    for (int t = 0; t < NT; t++) acc[t] = (f32x4){0.f, 0.f, 0.f, 0.f};

    const _Float16* hrow = &Hs[(wv * 16 + arow) * DP];
#pragma unroll
    for (int s = 0; s < NS; s++) {
        f16x8 a = *(const f16x8*)(hrow + s * 32 + agrp * 8);
        const _Float16* wb = Wf + (size_t)s * NT * 512 + l * 8;
#pragma unroll
        for (int t = 0; t < NT; t++) {
            f16x8 b = *(const f16x8*)(wb + (size_t)t * 512);
            acc[t] = __builtin_amdgcn_mfma_f32_16x16x32_f16(a, b, acc[t], 0, 0, 0);
        }
    }

    int rbase = wv * 16 + agrp * 4;
    float dv4[4] = {1.f, 1.f, 1.f, 1.f};
    if (DINVOUT) {
#pragma unroll
        for (int r = 0; r < 4; r++)
            if (rbase + r < nv) dv4[r] = dinv[node0 + rbase + r];
    }
    float sa[NT], qa[NT];
#pragma unroll
    for (int t = 0; t < NT; t++) {
        int col = t * 16 + arow;
        float bcol = BIAS ? bias[col] : 0.f;
        float ssum = 0.f, qsum = 0.f;
#pragma unroll
        for (int r = 0; r < 4; r++) {
            int nn = rbase + r;
            bool valid = nn < nv;
            float v = acc[t][r];
            if (DINVOUT) v *= dv4[r];
            v += bcol;
            v = valid ? v : 0.f;
            if (valid) {
                size_t oi = (size_t)(node0 + nn) * DOUT + col;
                if (HALFOUT) ((__half*)Out)[oi] = __float2half(v);
                else ((float*)Out)[oi] = v;
            }
            ssum += v;
            qsum += v * v;
        }
        sa[t] = ssum;
        qa[t] = qsum;
    }

    if constexpr (STATS) {
        __shared__ float ps[4][DOUT], pq[4][DOUT];
#pragma unroll
        for (int t = 0; t < NT; t++) {
            float s = sa[t], q = qa[t];
            s += __shfl_xor(s, 16, 64); q += __shfl_xor(q, 16, 64);
            s += __shfl_xor(s, 32, 64); q += __shfl_xor(q, 32, 64);
            if (l < 16) { ps[wv][t * 16 + l] = s; pq[wv][t * 16 + l] = q; }
        }
        __syncthreads();
        if (threadIdx.x < DOUT) {
            float t1 = ps[0][threadIdx.x] + ps[1][threadIdx.x] +
                       ps[2][threadIdx.x] + ps[3][threadIdx.x];
            float t2 = pq[0][threadIdx.x] + pq[1][threadIdx.x] +
                       pq[2][threadIdx.x] + pq[3][threadIdx.x];
            int cp = (blockIdx.x & 63) * 2 * DOUT;
            atomicAdd(&tmp[cp + threadIdx.x], (double)t1);
            atomicAdd(&tmp[cp + DOUT + threadIdx.x], (double)t2);
        }
    }
}

// ---- fold 64 tmp copies -> per-channel scale/shift floats ----
template <int D>
__global__ void finalize_tmp_kernel(const double* __restrict__ tmp,
                                    const float* __restrict__ g, const float* __restrict__ be,
                                    float* __restrict__ scale, float* __restrict__ shift, int n) {
    int c = threadIdx.x;
    if (c < D) {
        double s = 0.0, q = 0.0;
        for (int gg = 0; gg < 64; gg++) {
            s += tmp[gg * 2 * D + c];
            q += tmp[gg * 2 * D + D + c];
        }
        double mu = s / n;
        double var = q / n - mu * mu;
        double inv = 1.0 / sqrt(var + 1e-5);
        double sc = (double)g[c] * inv;
        scale[c] = (float)sc;
        shift[c] = (float)((double)be[c] - mu * sc);
    }
}

// ---- fold 64 tmp copies -> raw stats sums (for norm_pool) ----
template <int D>
__global__ void combine_kernel(const double* __restrict__ tmp, double* __restrict__ stats) {
    int t = threadIdx.x;
    if (t < 2 * D) {
        double s = 0.0;
        for (int gg = 0; gg < 64; gg++) s += tmp[gg * 2 * D + t];
        stats[t] = s;
    }
}

// ---- layer-3: BN normalize + GELU + residual(x) + mean-pool accumulate ----
__global__ __launch_bounds__(256) void norm_pool_kernel(const float* __restrict__ X3,
                                                        const float* __restrict__ x0,
                                                        const double* __restrict__ stats,
                                                        const float* __restrict__ gw,
                                                        const float* __restrict__ be,
                                                        double* __restrict__ pool, int n) {
    constexpr int D = 64;
    constexpr int RPB = 4;
    int c = threadIdx.x % D;
    double mu = stats[c] / n;
    double var = stats[c + D] / n - mu * mu;
    double inv = 1.0 / sqrt(var + 1e-5);
    float scale = (float)((double)gw[c] * inv);
    float shift = (float)((double)be[c] - mu * (double)gw[c] * inv);
    int r0 = threadIdx.x / D;
    int rowsPerGrid = gridDim.x * RPB;
    double s = 0.0;
    for (int r = blockIdx.x * RPB + r0; r < n; r += rowsPerGrid) {
        size_t idx = (size_t)r * D + c;
        float t = fmaf(X3[idx], scale, shift);
        float res = x0[idx] + gelu_f(t);
        s += res;
    }
    __shared__ double sh[256];
    sh[threadIdx.x] = s;
    __syncthreads();
    if (threadIdx.x < D) {
#pragma unroll
        for (int j = 1; j < RPB; j++) s += sh[threadIdx.x + j * D];
        atomicAdd(&pool[c], s);
    }
}

// ---- head MLP: 64 ->128 ->64 ->32 ->1, single block ----
__global__ __launch_bounds__(128) void mlp_kernel(const double* __restrict__ pool,
                                                  const float* __restrict__ w1, const float* __restrict__ b1,
                                                  const float* __restrict__ w2, const float* __restrict__ b2,
                                                  const float* __restrict__ w3, const float* __restrict__ b3,
                                                  const float* __restrict__ w4, const float* __restrict__ b4,
                                                  float* __restrict__ out, int n) {
    __shared__ float v0[64], h1[128], h2[64], h3[32];
    int t = threadIdx.x;
    if (t < 64) v0[t] = (float)(pool[t] / (double)n);
    __syncthreads();
    if (t < 128) {
        float a = b1[t];
        for (int k = 0; k < 64; k++) a = fmaf(v0[k], w1[k * 128 + t], a);
        h1[t] = gelu_f(a);
    }
    __syncthreads();
    if (t < 64) {
        float a = b2[t];
        for (int k = 0; k < 128; k++) a = fmaf(h1[k], w2[k * 64 + t], a);
        h2[t] = gelu_f(a);
    }
    __syncthreads();
    if (t < 32) {
        float a = b3[t];
        for (int k = 0; k < 64; k++) a = fmaf(h2[k], w3[k * 32 + t], a);
        h3[t] = gelu_f(a);
    }
    __syncthreads();
    if (t == 0) {
        float a = b4[0];
        for (int k = 0; k < 32; k++) a = fmaf(h3[k], w4[k], a);
        out[0] = a;
    }
}

extern "C" void kernel_launch(void* const* d_in, const int* in_sizes, int n_in,
                              void* d_out, int out_size, void* d_ws, size_t ws_size,
                              hipStream_t stream) {
    const float* x    = (const float*)d_in[0];
    const int*   ei   = (const int*)d_in[1];
    const float* W1   = (const float*)d_in[2];
    const float* b1   = (const float*)d_in[3];
    const float* g1   = (const float*)d_in[4];
    const float* be1  = (const float*)d_in[5];
    const float* W2   = (const float*)d_in[6];
    const float* b2   = (const float*)d_in[7];
    const float* g2   = (const float*)d_in[8];
    const float* be2  = (const float*)d_in[9];
    const float* W3   = (const float*)d_in[10];
    const float* b3   = (const float*)d_in[11];
    const float* g3   = (const float*)d_in[12];
    const float* be3  = (const float*)d_in[13];
    const float* fc1w = (const float*)d_in[14];
    const float* fc1b = (const float*)d_in[15];
    const float* fc2w = (const float*)d_in[16];
    const float* fc2b = (const float*)d_in[17];
    const float* fc3w = (const float*)d_in[18];
    const float* fc3b = (const float*)d_in[19];
    const float* fc4w = (const float*)d_in[20];
    const float* fc4b = (const float*)d_in[21];

    const int N = in_sizes[0] / 64;
    const int E = in_sizes[1] / 2;
    const int* e_row = ei;       // source
    const int* e_col = ei + E;   // target (aggregation index)
    const int nbuckets = (N + 255) >> 8;

    // ---- workspace layout (~112 MB) ----
    char* ws = (char*)d_ws;
    size_t off = 0;
    double* pool   = (double*)(ws + off); off += 64 * sizeof(double);
    double* tmp1   = (double*)(ws + off); off += 64 * 256 * sizeof(double);  // gemm1 stats spread
    double* tmp2   = (double*)(ws + off); off += 64 * 256 * sizeof(double);  // agg2 stats spread
    double* tmp3   = (double*)(ws + off); off += 64 * 128 * sizeof(double);  // agg3 stats spread
    double* stats3 = (double*)(ws + off); off += 128 * sizeof(double);
    const int NDBL = 64 + 64 * 256 * 2 + 64 * 128 + 128;  // zeroed by init
    float* scale1 = (float*)(ws + off); off += 128 * sizeof(float);
    float* shift1 = (float*)(ws + off); off += 128 * sizeof(float);
    float* scale2 = (float*)(ws + off); off += 128 * sizeof(float);
    float* shift2 = (float*)(ws + off); off += 128 * sizeof(float);
    _Float16* Wf1 = (_Float16*)(ws + off); off += 64 * 128 * sizeof(_Float16);
    _Float16* Wf2 = (_Float16*)(ws + off); off += 128 * 128 * sizeof(_Float16);
    _Float16* Wf3 = (_Float16*)(ws + off); off += 128 * 64 * sizeof(_Float16);
    float* deg   = (float*)(ws + off); off += (size_t)N * sizeof(float);
    float* dinv  = (float*)(ws + off); off += (size_t)N * sizeof(float);
    off = (off + 15) & ~(size_t)15;
    int* offs       = (int*)(ws + off); off += (size_t)N * sizeof(int);
    int* bucketCnt  = (int*)(ws + off); off += 512 * sizeof(int);
    int* bucketBase = (int*)(ws + off); off += 520 * sizeof(int);
    int* bcur       = (int*)(ws + off); off += 512 * sizeof(int);
    int* csr     = (int*)(ws + off); off += (size_t)E * sizeof(int);
    unsigned int* stage = (unsigned int*)(ws + off); off += (size_t)E * sizeof(unsigned int);
    off = (off + 255) & ~(size_t)255;
    __half* Ut   = (__half*)(ws + off); off += (size_t)N * 128 * sizeof(__half);  // fp16 gather table
    float* A1    = (float*)(ws + off);  off += (size_t)N * 64 * sizeof(float);    // agg1 out (fp32)
    float* H     = (float*)(ws + off);  off += (size_t)N * 128 * sizeof(float);   // fp32 row-major
    __half* xh   = Ut;  // alias: xh dead after agg1, before gemm2 writes Ut

    const int nb256 = (N + 255) / 256;
    const int eblk = (E + EPB - 1) / EPB;
    const int gblk = (N + 63) / 64;

    // CSR build: histogram -> scan -> stage -> finalize (deg/dinv/offs/csr)
    init_kernel<<<nb256, 256, 0, stream>>>(pool, NDBL, bucketCnt);
    coarse_count_kernel<<<eblk, 512, 0, stream>>>(e_col, bucketCnt, E, nbuckets);
    bucket_scan_kernel<<<1, 512, 0, stream>>>(bucketCnt, bucketBase, bcur, nbuckets, E);
    binstage_kernel<<<eblk, 512, 0, stream>>>(e_row, e_col, bcur, stage, E, nbuckets);
    bucket_finalize_kernel<<<nbuckets, 256, 0, stream>>>(stage, bucketBase, deg, dinv,
                                                         offs, csr, N);

    // W -> fragment-ordered fp16 (tiny, once)
    wconv_kernel<64, 128><<<32, 256, 0, stream>>>(W1, Wf1);
    wconv_kernel<128, 128><<<64, 256, 0, stream>>>(W2, Wf2);
    wconv_kernel<128, 64><<<32, 256, 0, stream>>>(W3, Wf3);

    // Layer 1: x -> fp16 (dinv-scaled); agg 64-dim -> A1; MFMA GEMM(+b1,+stats) -> H1
    halfconv_kernel<<<(N * 8 + 255) / 256, 256, 0, stream>>>(x, dinv, xh, N);
    agg_kernel<64, false, false><<<(N + 31) / 32, 256, 0, stream>>>(
        xh, csr, offs, deg, dinv, nullptr, A1, nullptr, N);
    mgemm_kernel<64, 128, false, true, false, false, true><<<gblk, 256, 0, stream>>>(
        A1, Wf1, nullptr, nullptr, b1, nullptr, H, tmp1, N);
    finalize_tmp_kernel<128><<<1, 128, 0, stream>>>(tmp1, g1, be1, scale1, shift1, N);

    // Layer 2: MFMA GEMM (BN1+GELU fused, dinv prescale, fp16 out) -> Ut; agg -> H2
    mgemm_kernel<128, 128, true, false, true, true, false><<<gblk, 256, 0, stream>>>(
        H, Wf2, scale1, shift1, nullptr, dinv, Ut, nullptr, N);
    agg_kernel<128, true, true><<<(N + 15) / 16, 256, 0, stream>>>(
        Ut, csr, offs, deg, dinv, b2, H, tmp2, N);
    finalize_tmp_kernel<128><<<1, 128, 0, stream>>>(tmp2, g2, be2, scale2, shift2, N);

    // Layer 3: MFMA GEMM (BN2+GELU fused, dinv prescale, fp16 out 64) -> Ut; agg -> H3
    mgemm_kernel<128, 64, true, false, true, true, false><<<gblk, 256, 0, stream>>>(
        H, Wf3, scale2, shift2, nullptr, dinv, Ut, nullptr, N);
    agg_kernel<64, true, true><<<(N + 31) / 32, 256, 0, stream>>>(
        Ut, csr, offs, deg, dinv, b3, H, tmp3, N);
    combine_kernel<64><<<1, 128, 0, stream>>>(tmp3, stats3);

    // Epilogue: BN3+GELU+residual+meanpool, then head MLP
    norm_pool_kernel<<<1024, 256, 0, stream>>>(H, x, stats3, g3, be3, pool, N);
    mlp_kernel<<<1, 128, 0, stream>>>(pool, fc1w, fc1b, fc2w, fc2b, fc3w, fc3b,
                                      fc4w, fc4b, (float*)d_out, N);
}